// Round 9
// baseline (807.954 us; speedup 1.0000x reference)
//
#include <hip/hip_runtime.h>

// GCN forward: mid = relu(spmm(A, x@W1) + b1); out = spmm(A, mid@W2) + b2
// N=100000, F=512, H=256, C=40, E=3.2M.
//
// R11 changes vs R10/R8 (R10 = rowsort REGRESSED 658->756: sort cost >>
// locality gain; reverted. R10's counters exposed gemm1 = 121.7us at
// MfmaUtil 8.4%, Occ 27%, 7.6M LDS bank conflicts -> latency/occupancy
// bound on the LDS-staging structure):
//  - rowsort removed; edge path back to verified R8 (658.0us) exactly.
//  - gemm1/gemm2 rewritten LDS-FREE: each lane loads its MFMA A/B fragment
//    directly from global (A: 4 lanes/row = 128B coalesced from x; B: per-nt
//    16 rows x 64B full lines from L2-resident W1T/W2T). No __shared__, no
//    barriers, no bank conflicts; 17 independent loads/k-step pipeline
//    freely. Same MFMA ops in same order -> bit-identical numerics.
//    __launch_bounds__(256,4) for >=4 waves/SIMD.

typedef __bf16 bf16;
typedef __bf16 bf16x8 __attribute__((ext_vector_type(8)));
typedef float floatx4 __attribute__((ext_vector_type(4)));
typedef float floatx2 __attribute__((ext_vector_type(2)));

#define NBMAX 400

// ---------------- weight conversion ----------------
__global__ __launch_bounds__(256) void conv_w(const float* __restrict__ W1,
                                              const float* __restrict__ W2,
                                              bf16* __restrict__ W1T,
                                              bf16* __restrict__ W2T) {
  int i = blockIdx.x * 256 + threadIdx.x;
  if (i < 512 * 256) {             // W1 [512][256] -> W1T [256][512]
    int k = i >> 8, n = i & 255;
    W1T[n * 512 + k] = (bf16)W1[i];
  }
  int j = i - 512 * 256;
  if (j >= 0 && j < 48 * 256) {    // W2 [256][40] -> W2T [48][256], pad rows 40..47
    int n = j >> 8, k = j & 255;
    W2T[j] = (n < 40) ? (bf16)W2[k * 40 + n] : (bf16)0.0f;
  }
}

// ---------------- partition stage 1: bucket histogram (persisted per block) ----
__global__ __launch_bounds__(256) void bhist_kernel(const int* __restrict__ er,
                                                    int* __restrict__ gbcount,
                                                    int* __restrict__ blkcnt,
                                                    int E, int NB, int EBLK) {
  __shared__ int cnt[NBMAX];
  const int t = threadIdx.x;
  for (int b = t; b < NB; b += 256) cnt[b] = 0;
  __syncthreads();
  const int base = blockIdx.x * 8192;
#pragma unroll
  for (int k = 0; k < 8; k++) {
    int i = base + k * 1024 + t * 4;
    if (i < E) {  // E % 4 == 0
      int4 r = *(const int4*)(er + i);
      atomicAdd(&cnt[r.x >> 8], 1);
      atomicAdd(&cnt[r.y >> 8], 1);
      atomicAdd(&cnt[r.z >> 8], 1);
      atomicAdd(&cnt[r.w >> 8], 1);
    }
  }
  __syncthreads();
  for (int b = t; b < NB; b += 256) {
    int c = cnt[b];
    blkcnt[b * EBLK + blockIdx.x] = c;
    if (c) atomicAdd(&gbcount[b], c);
  }
}

// ---------------- partition stage 2: bucket scan (1 block, 512 thr) ----------------
__global__ __launch_bounds__(512) void bscan_kernel(const int* __restrict__ gbcount,
                                                    int* __restrict__ bstart, int NB) {
  __shared__ int wsum[8];
  const int t = threadIdx.x;
  const int lane = t & 63, wave = t >> 6;
  int v = (t < NB) ? gbcount[t] : 0;
  int incl = v;
#pragma unroll
  for (int d = 1; d < 64; d <<= 1) {
    int o = __shfl_up(incl, d, 64);
    if (lane >= d) incl += o;
  }
  if (lane == 63) wsum[wave] = incl;
  __syncthreads();
  int off = 0;
#pragma unroll
  for (int w = 0; w < 8; w++)
    if (w < wave) off += wsum[w];
  int excl = off + incl - v;
  if (t <= NB) bstart[t] = excl;   // bstart[NB] = E
}

// ---------------- partition stage 2b: per-bucket cross-block scan ----------------
// block b: blkoff[b*EBLK + j] = bstart[b] + sum(blkcnt[b*EBLK + 0..j-1])
__global__ __launch_bounds__(512) void bscan2_kernel(const int* __restrict__ blkcnt,
                                                     const int* __restrict__ bstart,
                                                     int* __restrict__ blkoff, int EBLK) {
  __shared__ int wsum[8];
  const int b = blockIdx.x, t = threadIdx.x;
  const int lane = t & 63, wave = t >> 6;
  int v = (t < EBLK) ? blkcnt[b * EBLK + t] : 0;
  int incl = v;
#pragma unroll
  for (int d = 1; d < 64; d <<= 1) {
    int o = __shfl_up(incl, d, 64);
    if (lane >= d) incl += o;
  }
  if (lane == 63) wsum[wave] = incl;
  __syncthreads();
  int off = 0;
#pragma unroll
  for (int w = 0; w < 8; w++)
    if (w < wave) off += wsum[w];
  if (t < EBLK) blkoff[b * EBLK + t] = bstart[b] + off + incl - v;
}

// ---------------- partition stage 3: scatter into buckets ----------------
// epack_b[i] = ( (row&255)<<17 | col , val )
__global__ __launch_bounds__(256) void partA_kernel(
    const int* __restrict__ er, const int* __restrict__ ec, const float* __restrict__ ev,
    const int* __restrict__ blkoff, int2* __restrict__ epack_b, int E, int NB, int EBLK) {
  __shared__ int cur[NBMAX];
  const int t = threadIdx.x;
  for (int b = t; b < NB; b += 256) cur[b] = blkoff[b * EBLK + blockIdx.x];
  __syncthreads();
  const int base = blockIdx.x * 8192;
#pragma unroll
  for (int k = 0; k < 8; k++) {
    int i = base + k * 1024 + t * 4;
    if (i < E) {
      int4 r = *(const int4*)(er + i);
      int4 c = *(const int4*)(ec + i);
      float4 v = *(const float4*)(ev + i);
      int s0 = atomicAdd(&cur[r.x >> 8], 1);
      epack_b[s0] = make_int2(((r.x & 255) << 17) | c.x, __float_as_int(v.x));
      int s1 = atomicAdd(&cur[r.y >> 8], 1);
      epack_b[s1] = make_int2(((r.y & 255) << 17) | c.y, __float_as_int(v.y));
      int s2 = atomicAdd(&cur[r.z >> 8], 1);
      epack_b[s2] = make_int2(((r.z & 255) << 17) | c.z, __float_as_int(v.z));
      int s3 = atomicAdd(&cur[r.w >> 8], 1);
      epack_b[s3] = make_int2(((r.w & 255) << 17) | c.w, __float_as_int(v.w));
    }
  }
}

// ---------------- partition stage 4: per-bucket CSR finalize ----------------
__global__ __launch_bounds__(256) void partB_kernel(
    const int2* __restrict__ epack_b, const int* __restrict__ bstart,
    int2* __restrict__ epack_f, int* __restrict__ rp, int M) {
  __shared__ int rcnt[256];
  __shared__ int rcur[256];
  __shared__ int wsum[4];
  const int b = blockIdx.x, t = threadIdx.x;
  const int s = bstart[b];
  const int e_ = bstart[b + 1];
  rcnt[t] = 0;
  __syncthreads();
  for (int i = s + t; i < e_; i += 256) {
    unsigned int ro = ((unsigned int)epack_b[i].x) >> 17;
    atomicAdd(&rcnt[ro], 1);
  }
  __syncthreads();
  const int lane = t & 63, wave = t >> 6;
  int v = rcnt[t];
  int incl = v;
#pragma unroll
  for (int d = 1; d < 64; d <<= 1) {
    int o = __shfl_up(incl, d, 64);
    if (lane >= d) incl += o;
  }
  if (lane == 63) wsum[wave] = incl;
  __syncthreads();
  int off = 0;
#pragma unroll
  for (int w = 0; w < 4; w++)
    if (w < wave) off += wsum[w];
  rcur[t] = s + off + incl - v;
  __syncthreads();
  for (int i = s + t; i < e_; i += 256) {
    int2 m = epack_b[i];
    unsigned int ro = ((unsigned int)m.x) >> 17;
    int slot = atomicAdd(&rcur[ro], 1);
    epack_f[slot] = make_int2(m.x & 0x1FFFF, m.y);
  }
  __syncthreads();
  int r = (b << 8) + t;
  if (r < M) rp[r] = rcur[t];  // end of row r
}

// ---------------- GEMM1: T1f8 = fp8(x @ W1), [M][64 uints], LDS-free ----------------
// T1f8 layout: uint i of row n packs features {i, i+64, i+128, i+192} (e4m3).
// Each lane loads its MFMA fragments directly from global:
//   A: x[m0+wave*16+l16][k0+quad*8..+8]  (4 lanes/row -> 128B coalesced)
//   B: W1T[(nt*16+l16)*512 + k0 + quad*8..+8]  (per nt: 16 rows x 64B lines, L2)
__global__ __launch_bounds__(256, 4) void gemm1_kernel(const float* __restrict__ x,
                                                       const bf16* __restrict__ W1T,
                                                       unsigned int* __restrict__ T1f8, int M) {
  const int t = threadIdx.x;
  const int wave = t >> 6, lane = t & 63;
  const int quad = lane >> 4, l16 = lane & 15;
  const int m0 = blockIdx.x * 64;
  floatx4 acc[16] = {};

  const int arow = m0 + wave * 16 + l16;
  const bool arow_ok = (arow < M);
  const float* a_src = x + (size_t)arow * 512 + quad * 8;
  const bf16* b_base = W1T + (size_t)l16 * 512 + quad * 8;

  for (int k0 = 0; k0 < 512; k0 += 32) {
    bf16x8 a;
    {
      float4 f0 = {0, 0, 0, 0}, f1 = {0, 0, 0, 0};
      if (arow_ok) {
        const float4* p = (const float4*)(a_src + k0);
        f0 = p[0]; f1 = p[1];
      }
      a[0] = (bf16)f0.x; a[1] = (bf16)f0.y; a[2] = (bf16)f0.z; a[3] = (bf16)f0.w;
      a[4] = (bf16)f1.x; a[5] = (bf16)f1.y; a[6] = (bf16)f1.z; a[7] = (bf16)f1.w;
    }
#pragma unroll
    for (int nt = 0; nt < 16; nt++) {
      bf16x8 b = *(const bf16x8*)(b_base + (size_t)nt * 16 * 512 + k0);
      acc[nt] = __builtin_amdgcn_mfma_f32_16x16x32_bf16(a, b, acc[nt], 0, 0, 0);
    }
  }
  const int row_base = m0 + wave * 16 + quad * 4;
#pragma unroll
  for (int nt0 = 0; nt0 < 4; nt0++) {
#pragma unroll
    for (int j = 0; j < 4; j++) {
      int gr = row_base + j;
      if (gr < M) {
        int p = 0;
        p = __builtin_amdgcn_cvt_pk_fp8_f32(acc[nt0][j],     acc[nt0 + 4][j],  p, false);
        p = __builtin_amdgcn_cvt_pk_fp8_f32(acc[nt0 + 8][j], acc[nt0 + 12][j], p, true);
        T1f8[(size_t)gr * 64 + nt0 * 16 + l16] = (unsigned int)p;
      }
    }
  }
}

// ---------------- SpMM1: mid = relu(gather-sum(T1f8) + b1) ----------------
// lane reads uint `lane` of each gathered row -> features {lane, lane+64,
// lane+128, lane+192}. 16 edges in flight per wave-iter (R8 body).
__global__ __launch_bounds__(256, 6) void spmm1_kernel(
    const int* __restrict__ rp, const int2* __restrict__ epack,
    const unsigned int* __restrict__ T1f8, const float* __restrict__ b1,
    float* __restrict__ mid, int M) {
  const int lane = threadIdx.x & 63;
  const int r = blockIdx.x * 4 + (threadIdx.x >> 6);
  if (r >= M) return;
  const int eend = rp[r];
  int e = (r == 0) ? 0 : rp[r - 1];
  float a0 = 0.f, a1 = 0.f, a2 = 0.f, a3 = 0.f;
  if (e < eend && (e & 1)) {  // align to even for int4 loads
    int2 m = epack[e];
    float v = __int_as_float(m.y);
    unsigned int u = T1f8[(((unsigned)m.x) << 6) | lane];
    floatx2 lo = __builtin_amdgcn_cvt_pk_f32_fp8(u, false);
    floatx2 hi = __builtin_amdgcn_cvt_pk_f32_fp8(u, true);
    a0 += v * lo[0]; a1 += v * lo[1]; a2 += v * hi[0]; a3 += v * hi[1];
    e++;
  }
  // ---- main: 16 edges in flight ----
  for (; e + 15 < eend; e += 16) {
    int4 pA = *(const int4*)(epack + e);
    int4 pB = *(const int4*)(epack + e + 2);
    int4 pC = *(const int4*)(epack + e + 4);
    int4 pD = *(const int4*)(epack + e + 6);
    int4 pE = *(const int4*)(epack + e + 8);
    int4 pF = *(const int4*)(epack + e + 10);
    int4 pG = *(const int4*)(epack + e + 12);
    int4 pH = *(const int4*)(epack + e + 14);
    unsigned int u0  = T1f8[(((unsigned)pA.x) << 6) | lane];
    unsigned int u1  = T1f8[(((unsigned)pA.z) << 6) | lane];
    unsigned int u2  = T1f8[(((unsigned)pB.x) << 6) | lane];
    unsigned int u3  = T1f8[(((unsigned)pB.z) << 6) | lane];
    unsigned int u4  = T1f8[(((unsigned)pC.x) << 6) | lane];
    unsigned int u5  = T1f8[(((unsigned)pC.z) << 6) | lane];
    unsigned int u6  = T1f8[(((unsigned)pD.x) << 6) | lane];
    unsigned int u7  = T1f8[(((unsigned)pD.z) << 6) | lane];
    unsigned int u8  = T1f8[(((unsigned)pE.x) << 6) | lane];
    unsigned int u9  = T1f8[(((unsigned)pE.z) << 6) | lane];
    unsigned int u10 = T1f8[(((unsigned)pF.x) << 6) | lane];
    unsigned int u11 = T1f8[(((unsigned)pF.z) << 6) | lane];
    unsigned int u12 = T1f8[(((unsigned)pG.x) << 6) | lane];
    unsigned int u13 = T1f8[(((unsigned)pG.z) << 6) | lane];
    unsigned int u14 = T1f8[(((unsigned)pH.x) << 6) | lane];
    unsigned int u15 = T1f8[(((unsigned)pH.z) << 6) | lane];
    float v0  = __int_as_float(pA.y), v1  = __int_as_float(pA.w);
    float v2  = __int_as_float(pB.y), v3  = __int_as_float(pB.w);
    float v4  = __int_as_float(pC.y), v5  = __int_as_float(pC.w);
    float v6  = __int_as_float(pD.y), v7  = __int_as_float(pD.w);
    float v8  = __int_as_float(pE.y), v9  = __int_as_float(pE.w);
    float v10 = __int_as_float(pF.y), v11 = __int_as_float(pF.w);
    float v12 = __int_as_float(pG.y), v13 = __int_as_float(pG.w);
    float v14 = __int_as_float(pH.y), v15 = __int_as_float(pH.w);
    floatx2 lo, hi;
    lo = __builtin_amdgcn_cvt_pk_f32_fp8(u0, false);
    hi = __builtin_amdgcn_cvt_pk_f32_fp8(u0, true);
    a0 += v0 * lo[0]; a1 += v0 * lo[1]; a2 += v0 * hi[0]; a3 += v0 * hi[1];
    lo = __builtin_amdgcn_cvt_pk_f32_fp8(u1, false);
    hi = __builtin_amdgcn_cvt_pk_f32_fp8(u1, true);
    a0 += v1 * lo[0]; a1 += v1 * lo[1]; a2 += v1 * hi[0]; a3 += v1 * hi[1];
    lo = __builtin_amdgcn_cvt_pk_f32_fp8(u2, false);
    hi = __builtin_amdgcn_cvt_pk_f32_fp8(u2, true);
    a0 += v2 * lo[0]; a1 += v2 * lo[1]; a2 += v2 * hi[0]; a3 += v2 * hi[1];
    lo = __builtin_amdgcn_cvt_pk_f32_fp8(u3, false);
    hi = __builtin_amdgcn_cvt_pk_f32_fp8(u3, true);
    a0 += v3 * lo[0]; a1 += v3 * lo[1]; a2 += v3 * hi[0]; a3 += v3 * hi[1];
    lo = __builtin_amdgcn_cvt_pk_f32_fp8(u4, false);
    hi = __builtin_amdgcn_cvt_pk_f32_fp8(u4, true);
    a0 += v4 * lo[0]; a1 += v4 * lo[1]; a2 += v4 * hi[0]; a3 += v4 * hi[1];
    lo = __builtin_amdgcn_cvt_pk_f32_fp8(u5, false);
    hi = __builtin_amdgcn_cvt_pk_f32_fp8(u5, true);
    a0 += v5 * lo[0]; a1 += v5 * lo[1]; a2 += v5 * hi[0]; a3 += v5 * hi[1];
    lo = __builtin_amdgcn_cvt_pk_f32_fp8(u6, false);
    hi = __builtin_amdgcn_cvt_pk_f32_fp8(u6, true);
    a0 += v6 * lo[0]; a1 += v6 * lo[1]; a2 += v6 * hi[0]; a3 += v6 * hi[1];
    lo = __builtin_amdgcn_cvt_pk_f32_fp8(u7, false);
    hi = __builtin_amdgcn_cvt_pk_f32_fp8(u7, true);
    a0 += v7 * lo[0]; a1 += v7 * lo[1]; a2 += v7 * hi[0]; a3 += v7 * hi[1];
    lo = __builtin_amdgcn_cvt_pk_f32_fp8(u8, false);
    hi = __builtin_amdgcn_cvt_pk_f32_fp8(u8, true);
    a0 += v8 * lo[0]; a1 += v8 * lo[1]; a2 += v8 * hi[0]; a3 += v8 * hi[1];
    lo = __builtin_amdgcn_cvt_pk_f32_fp8(u9, false);
    hi = __builtin_amdgcn_cvt_pk_f32_fp8(u9, true);
    a0 += v9 * lo[0]; a1 += v9 * lo[1]; a2 += v9 * hi[0]; a3 += v9 * hi[1];
    lo = __builtin_amdgcn_cvt_pk_f32_fp8(u10, false);
    hi = __builtin_amdgcn_cvt_pk_f32_fp8(u10, true);
    a0 += v10 * lo[0]; a1 += v10 * lo[1]; a2 += v10 * hi[0]; a3 += v10 * hi[1];
    lo = __builtin_amdgcn_cvt_pk_f32_fp8(u11, false);
    hi = __builtin_amdgcn_cvt_pk_f32_fp8(u11, true);
    a0 += v11 * lo[0]; a1 += v11 * lo[1]; a2 += v11 * hi[0]; a3 += v11 * hi[1];
    lo = __builtin_amdgcn_cvt_pk_f32_fp8(u12, false);
    hi = __builtin_amdgcn_cvt_pk_f32_fp8(u12, true);
    a0 += v12 * lo[0]; a1 += v12 * lo[1]; a2 += v12 * hi[0]; a3 += v12 * hi[1];
    lo = __builtin_amdgcn_cvt_pk_f32_fp8(u13, false);
    hi = __builtin_amdgcn_cvt_pk_f32_fp8(u13, true);
    a0 += v13 * lo[0]; a1 += v13 * lo[1]; a2 += v13 * hi[0]; a3 += v13 * hi[1];
    lo = __builtin_amdgcn_cvt_pk_f32_fp8(u14, false);
    hi = __builtin_amdgcn_cvt_pk_f32_fp8(u14, true);
    a0 += v14 * lo[0]; a1 += v14 * lo[1]; a2 += v14 * hi[0]; a3 += v14 * hi[1];
    lo = __builtin_amdgcn_cvt_pk_f32_fp8(u15, false);
    hi = __builtin_amdgcn_cvt_pk_f32_fp8(u15, true);
    a0 += v15 * lo[0]; a1 += v15 * lo[1]; a2 += v15 * hi[0]; a3 += v15 * hi[1];
  }
  // ---- 8-edge tail ----
  for (; e + 7 < eend; e += 8) {
    int4 p01 = *(const int4*)(epack + e);
    int4 p23 = *(const int4*)(epack + e + 2);
    int4 p45 = *(const int4*)(epack + e + 4);
    int4 p67 = *(const int4*)(epack + e + 6);
    unsigned int u0 = T1f8[(((unsigned)p01.x) << 6) | lane];
    unsigned int u1 = T1f8[(((unsigned)p01.z) << 6) | lane];
    unsigned int u2 = T1f8[(((unsigned)p23.x) << 6) | lane];
    unsigned int u3 = T1f8[(((unsigned)p23.z) << 6) | lane];
    unsigned int u4 = T1f8[(((unsigned)p45.x) << 6) | lane];
    unsigned int u5 = T1f8[(((unsigned)p45.z) << 6) | lane];
    unsigned int u6 = T1f8[(((unsigned)p67.x) << 6) | lane];
    unsigned int u7 = T1f8[(((unsigned)p67.z) << 6) | lane];
    float v0 = __int_as_float(p01.y), v1 = __int_as_float(p01.w);
    float v2 = __int_as_float(p23.y), v3 = __int_as_float(p23.w);
    float v4 = __int_as_float(p45.y), v5 = __int_as_float(p45.w);
    float v6 = __int_as_float(p67.y), v7 = __int_as_float(p67.w);
    floatx2 lo, hi;
    lo = __builtin_amdgcn_cvt_pk_f32_fp8(u0, false);
    hi = __builtin_amdgcn_cvt_pk_f32_fp8(u0, true);
    a0 += v0 * lo[0]; a1 += v0 * lo[1]; a2 += v0 * hi[0]; a3 += v0 * hi[1];
    lo = __builtin_amdgcn_cvt_pk_f32_fp8(u1, false);
    hi = __builtin_amdgcn_cvt_pk_f32_fp8(u1, true);
    a0 += v1 * lo[0]; a1 += v1 * lo[1]; a2 += v1 * hi[0]; a3 += v1 * hi[1];
    lo = __builtin_amdgcn_cvt_pk_f32_fp8(u2, false);
    hi = __builtin_amdgcn_cvt_pk_f32_fp8(u2, true);
    a0 += v2 * lo[0]; a1 += v2 * lo[1]; a2 += v2 * hi[0]; a3 += v2 * hi[1];
    lo = __builtin_amdgcn_cvt_pk_f32_fp8(u3, false);
    hi = __builtin_amdgcn_cvt_pk_f32_fp8(u3, true);
    a0 += v3 * lo[0]; a1 += v3 * lo[1]; a2 += v3 * hi[0]; a3 += v3 * hi[1];
    lo = __builtin_amdgcn_cvt_pk_f32_fp8(u4, false);
    hi = __builtin_amdgcn_cvt_pk_f32_fp8(u4, true);
    a0 += v4 * lo[0]; a1 += v4 * lo[1]; a2 += v4 * hi[0]; a3 += v4 * hi[1];
    lo = __builtin_amdgcn_cvt_pk_f32_fp8(u5, false);
    hi = __builtin_amdgcn_cvt_pk_f32_fp8(u5, true);
    a0 += v5 * lo[0]; a1 += v5 * lo[1]; a2 += v5 * hi[0]; a3 += v5 * hi[1];
    lo = __builtin_amdgcn_cvt_pk_f32_fp8(u6, false);
    hi = __builtin_amdgcn_cvt_pk_f32_fp8(u6, true);
    a0 += v6 * lo[0]; a1 += v6 * lo[1]; a2 += v6 * hi[0]; a3 += v6 * hi[1];
    lo = __builtin_amdgcn_cvt_pk_f32_fp8(u7, false);
    hi = __builtin_amdgcn_cvt_pk_f32_fp8(u7, true);
    a0 += v7 * lo[0]; a1 += v7 * lo[1]; a2 += v7 * hi[0]; a3 += v7 * hi[1];
  }
  for (; e + 3 < eend; e += 4) {
    int4 p01 = *(const int4*)(epack + e);
    int4 p23 = *(const int4*)(epack + e + 2);
    unsigned int u0 = T1f8[(((unsigned)p01.x) << 6) | lane];
    unsigned int u1 = T1f8[(((unsigned)p01.z) << 6) | lane];
    unsigned int u2 = T1f8[(((unsigned)p23.x) << 6) | lane];
    unsigned int u3 = T1f8[(((unsigned)p23.z) << 6) | lane];
    float v0 = __int_as_float(p01.y), v1 = __int_as_float(p01.w);
    float v2 = __int_as_float(p23.y), v3 = __int_as_float(p23.w);
    floatx2 lo, hi;
    lo = __builtin_amdgcn_cvt_pk_f32_fp8(u0, false);
    hi = __builtin_amdgcn_cvt_pk_f32_fp8(u0, true);
    a0 += v0 * lo[0]; a1 += v0 * lo[1]; a2 += v0 * hi[0]; a3 += v0 * hi[1];
    lo = __builtin_amdgcn_cvt_pk_f32_fp8(u1, false);
    hi = __builtin_amdgcn_cvt_pk_f32_fp8(u1, true);
    a0 += v1 * lo[0]; a1 += v1 * lo[1]; a2 += v1 * hi[0]; a3 += v1 * hi[1];
    lo = __builtin_amdgcn_cvt_pk_f32_fp8(u2, false);
    hi = __builtin_amdgcn_cvt_pk_f32_fp8(u2, true);
    a0 += v2 * lo[0]; a1 += v2 * lo[1]; a2 += v2 * hi[0]; a3 += v2 * hi[1];
    lo = __builtin_amdgcn_cvt_pk_f32_fp8(u3, false);
    hi = __builtin_amdgcn_cvt_pk_f32_fp8(u3, true);
    a0 += v3 * lo[0]; a1 += v3 * lo[1]; a2 += v3 * hi[0]; a3 += v3 * hi[1];
  }
  for (; e < eend; e++) {
    int2 m = epack[e];
    float v = __int_as_float(m.y);
    unsigned int u = T1f8[(((unsigned)m.x) << 6) | lane];
    floatx2 lo = __builtin_amdgcn_cvt_pk_f32_fp8(u, false);
    floatx2 hi = __builtin_amdgcn_cvt_pk_f32_fp8(u, true);
    a0 += v * lo[0]; a1 += v * lo[1]; a2 += v * hi[0]; a3 += v * hi[1];
  }
  // a0..a3 are features lane, lane+64, lane+128, lane+192
  float o0 = fmaxf(a0 + b1[lane],       0.f);
  float o1 = fmaxf(a1 + b1[lane + 64],  0.f);
  float o2 = fmaxf(a2 + b1[lane + 128], 0.f);
  float o3 = fmaxf(a3 + b1[lane + 192], 0.f);
  float* mrow = mid + (size_t)r * 256 + lane;
  mrow[0]   = o0;
  mrow[64]  = o1;
  mrow[128] = o2;
  mrow[192] = o3;
}

// ---------------- GEMM2: T2f8 = fp8(mid @ W2), [M][16 uints], LDS-free ----------------
// T2f8 layout: uint i of row n packs cols {i, i+16, i+32} (byte3 = 0).
__global__ __launch_bounds__(256, 4) void gemm2_kernel(const float* __restrict__ mid,
                                                       const bf16* __restrict__ W2T,
                                                       unsigned int* __restrict__ T2f8, int M) {
  const int t = threadIdx.x;
  const int wave = t >> 6, lane = t & 63;
  const int quad = lane >> 4, l16 = lane & 15;
  const int m0 = blockIdx.x * 64;
  floatx4 acc[3] = {};

  const int arow = m0 + wave * 16 + l16;
  const bool arow_ok = (arow < M);
  const float* a_src = mid + (size_t)arow * 256 + quad * 8;
  const bf16* b_base = W2T + (size_t)l16 * 256 + quad * 8;

  for (int k0 = 0; k0 < 256; k0 += 32) {
    bf16x8 a;
    {
      float4 f0 = {0, 0, 0, 0}, f1 = {0, 0, 0, 0};
      if (arow_ok) {
        const float4* p = (const float4*)(a_src + k0);
        f0 = p[0]; f1 = p[1];
      }
      a[0] = (bf16)f0.x; a[1] = (bf16)f0.y; a[2] = (bf16)f0.z; a[3] = (bf16)f0.w;
      a[4] = (bf16)f1.x; a[5] = (bf16)f1.y; a[6] = (bf16)f1.z; a[7] = (bf16)f1.w;
    }
#pragma unroll
    for (int nt = 0; nt < 3; nt++) {
      bf16x8 b = *(const bf16x8*)(b_base + (size_t)nt * 16 * 256 + k0);
      acc[nt] = __builtin_amdgcn_mfma_f32_16x16x32_bf16(a, b, acc[nt], 0, 0, 0);
    }
  }
  const int row_base = m0 + wave * 16 + quad * 4;
#pragma unroll
  for (int j = 0; j < 4; j++) {
    int gr = row_base + j;
    if (gr < M) {
      int p = 0;
      p = __builtin_amdgcn_cvt_pk_fp8_f32(acc[0][j], acc[1][j], p, false);
      p = __builtin_amdgcn_cvt_pk_fp8_f32(acc[2][j], 0.0f,      p, true);
      T2f8[(size_t)gr * 16 + l16] = (unsigned int)p;
    }
  }
}

// ---------------- SpMM2: out = gather-sum(T2f8) + b2 ----------------
// quarter-wave (16 lanes) per edge; 16 edges per wave-iter (4/group);
// lane q reads uint q -> cols {q, q+16, q+32}. shfl-tree combine.
__global__ __launch_bounds__(256, 6) void spmm2_kernel(
    const int* __restrict__ rp, const int2* __restrict__ epack,
    const unsigned int* __restrict__ T2f8, const float* __restrict__ b2,
    float* __restrict__ out2, int M) {
  const int lane = threadIdx.x & 63;
  const int r = blockIdx.x * 4 + (threadIdx.x >> 6);
  if (r >= M) return;
  const int q = lane & 15;
  const int g = lane >> 4;  // edge group 0..3
  const int eend = rp[r];
  int e = (r == 0) ? 0 : rp[r - 1];
  float a0 = 0.f, a1 = 0.f, a2 = 0.f;
  if (e < eend && (e & 1)) {  // align to even for int4 loads (group 0 takes it)
    if (g == 0) {
      int2 m = epack[e];
      float v = __int_as_float(m.y);
      unsigned int u = T2f8[(((unsigned)m.x) << 4) | q];
      floatx2 lo = __builtin_amdgcn_cvt_pk_f32_fp8(u, false);
      floatx2 hi = __builtin_amdgcn_cvt_pk_f32_fp8(u, true);
      a0 += v * lo[0]; a1 += v * lo[1]; a2 += v * hi[0];
    }
    e++;
  }
  // ---- main: 16 edges / wave-iter, group g: e+2g,e+2g+1,e+8+2g,e+8+2g+1 ----
  for (; e + 15 < eend; e += 16) {
    int4 m0 = *(const int4*)(epack + e + 2 * g);
    int4 m1 = *(const int4*)(epack + e + 8 + 2 * g);
    unsigned int u0 = T2f8[(((unsigned)m0.x) << 4) | q];
    unsigned int u1 = T2f8[(((unsigned)m0.z) << 4) | q];
    unsigned int u2 = T2f8[(((unsigned)m1.x) << 4) | q];
    unsigned int u3 = T2f8[(((unsigned)m1.z) << 4) | q];
    float v0 = __int_as_float(m0.y), v1 = __int_as_float(m0.w);
    float v2 = __int_as_float(m1.y), v3 = __int_as_float(m1.w);
    floatx2 lo, hi;
    lo = __builtin_amdgcn_cvt_pk_f32_fp8(u0, false);
    hi = __builtin_amdgcn_cvt_pk_f32_fp8(u0, true);
    a0 += v0 * lo[0]; a1 += v0 * lo[1]; a2 += v0 * hi[0];
    lo = __builtin_amdgcn_cvt_pk_f32_fp8(u1, false);
    hi = __builtin_amdgcn_cvt_pk_f32_fp8(u1, true);
    a0 += v1 * lo[0]; a1 += v1 * lo[1]; a2 += v1 * hi[0];
    lo = __builtin_amdgcn_cvt_pk_f32_fp8(u2, false);
    hi = __builtin_amdgcn_cvt_pk_f32_fp8(u2, true);
    a0 += v2 * lo[0]; a1 += v2 * lo[1]; a2 += v2 * hi[0];
    lo = __builtin_amdgcn_cvt_pk_f32_fp8(u3, false);
    hi = __builtin_amdgcn_cvt_pk_f32_fp8(u3, true);
    a0 += v3 * lo[0]; a1 += v3 * lo[1]; a2 += v3 * hi[0];
  }
  for (; e + 7 < eend; e += 8) {  // group g: edges e+2g, e+2g+1 via one int4
    int4 m = *(const int4*)(epack + e + 2 * g);
    float v0 = __int_as_float(m.y), v1 = __int_as_float(m.w);
    unsigned int u0 = T2f8[(((unsigned)m.x) << 4) | q];
    unsigned int u1 = T2f8[(((unsigned)m.z) << 4) | q];
    floatx2 l0 = __builtin_amdgcn_cvt_pk_f32_fp8(u0, false);
    floatx2 h0 = __builtin_amdgcn_cvt_pk_f32_fp8(u0, true);
    floatx2 l1 = __builtin_amdgcn_cvt_pk_f32_fp8(u1, false);
    floatx2 h1 = __builtin_amdgcn_cvt_pk_f32_fp8(u1, true);
    a0 += v0 * l0[0]; a1 += v0 * l0[1]; a2 += v0 * h0[0];
    a0 += v1 * l1[0]; a1 += v1 * l1[1]; a2 += v1 * h1[0];
  }
  for (; e + 3 < eend; e += 4) {  // group g: edge e+g
    int2 m = epack[e + g];
    float v = __int_as_float(m.y);
    unsigned int u = T2f8[(((unsigned)m.x) << 4) | q];
    floatx2 lo = __builtin_amdgcn_cvt_pk_f32_fp8(u, false);
    floatx2 hi = __builtin_amdgcn_cvt_pk_f32_fp8(u, true);
    a0 += v * lo[0]; a1 += v * lo[1]; a2 += v * hi[0];
  }
  if (e + g < eend) {  // tail: groups 0..(eend-e-1)
    int2 m = epack[e + g];
    float v = __int_as_float(m.y);
    unsigned int u = T2f8[(((unsigned)m.x) << 4) | q];
    floatx2 lo = __builtin_amdgcn_cvt_pk_f32_fp8(u, false);
    floatx2 hi = __builtin_amdgcn_cvt_pk_f32_fp8(u, true);
    a0 += v * lo[0]; a1 += v * lo[1]; a2 += v * hi[0];
  }
  a0 += __shfl_down(a0, 32, 64); a0 += __shfl_down(a0, 16, 64);
  a1 += __shfl_down(a1, 32, 64); a1 += __shfl_down(a1, 16, 64);
  a2 += __shfl_down(a2, 32, 64); a2 += __shfl_down(a2, 16, 64);
  if (lane < 16) {
    // a0..a2 are cols lane, lane+16, lane+32 (valid cols < 40)
    float* orow = out2 + (size_t)r * 40;
    orow[lane]      = a0 + b2[lane];
    orow[lane + 16] = a1 + b2[lane + 16];
    if (lane < 8) orow[lane + 32] = a2 + b2[lane + 32];
  }
}

// ---------------- launch ----------------
extern "C" void kernel_launch(void* const* d_in, const int* in_sizes, int n_in,
                              void* d_out, int out_size, void* d_ws, size_t ws_size,
                              hipStream_t stream) {
  const float* x        = (const float*)d_in[0];
  const int*   edge_row = (const int*)d_in[1];
  const int*   edge_col = (const int*)d_in[2];
  const float* edge_val = (const float*)d_in[3];
  const float* W1       = (const float*)d_in[4];
  const float* b1       = (const float*)d_in[5];
  const float* W2       = (const float*)d_in[6];
  const float* b2       = (const float*)d_in[7];
  const int M = in_sizes[0] / 512;  // 100000 nodes
  const int E = in_sizes[1];        // 3200000 edges
  const int NB = (M + 255) >> 8;    // 391 buckets
  const int EBLK = (E + 8191) / 8192;  // 391 blocks

  char* ws = (char*)d_ws;
  size_t off = 0;
  bf16* W1T     = (bf16*)(ws + off);  off += 512 * 256 * 2;
  bf16* W2T     = (bf16*)(ws + off);  off += 48 * 256 * 2;
  unsigned int* T1f8 = (unsigned int*)(ws + off); off += (size_t)M * 256;
  unsigned int* T2f8 = (unsigned int*)(ws + off); off += (size_t)M * 64;
  int* rp       = (int*)(ws + off);   off += (size_t)M * 4;
  int* gbcount  = (int*)(ws + off);   off += NBMAX * 4;
  int* bstart   = (int*)(ws + off);   off += (NBMAX + 1) * 4;
  int* blkcnt   = (int*)(ws + off);   off += (size_t)NB * EBLK * 4;
  int* blkoff   = (int*)(ws + off);   off += (size_t)NB * EBLK * 4;
  off = (off + 15) & ~(size_t)15;
  int2* epack_b = (int2*)(ws + off);  off += (size_t)E * 8;
  int2* epack_f = (int2*)(ws + off);  off += (size_t)E * 8;

  float* mid  = (float*)d_out;
  float* out2 = mid + (size_t)M * 256;

  hipMemsetAsync(gbcount, 0, NBMAX * 4, stream);
  conv_w<<<(512 * 256 + 48 * 256 + 255) / 256, 256, 0, stream>>>(W1, W2, W1T, W2T);
  bhist_kernel<<<EBLK, 256, 0, stream>>>(edge_row, gbcount, blkcnt, E, NB, EBLK);
  bscan_kernel<<<1, 512, 0, stream>>>(gbcount, bstart, NB);
  bscan2_kernel<<<NB, 512, 0, stream>>>(blkcnt, bstart, blkoff, EBLK);
  partA_kernel<<<EBLK, 256, 0, stream>>>(edge_row, edge_col, edge_val,
                                         blkoff, epack_b, E, NB, EBLK);
  partB_kernel<<<NB, 256, 0, stream>>>(epack_b, bstart, epack_f, rp, M);
  gemm1_kernel<<<(M + 63) / 64, 256, 0, stream>>>(x, W1T, T1f8, M);
  spmm1_kernel<<<(M + 3) / 4, 256, 0, stream>>>(rp, epack_f, T1f8, b1, mid, M);
  gemm2_kernel<<<(M + 63) / 64, 256, 0, stream>>>(mid, W2T, T2f8, M);
  spmm2_kernel<<<(M + 3) / 4, 256, 0, stream>>>(rp, epack_f, T2f8, b2, out2, M);
}

// Round 10
// 657.198 us; speedup vs baseline: 1.2294x; 1.2294x over previous
//
#include <hip/hip_runtime.h>

// GCN forward: mid = relu(spmm(A, x@W1) + b1); out = spmm(A, mid@W2) + b2
// N=100000, F=512, H=256, C=40, E=3.2M.
//
// R12 changes vs R11/R8 (R11 LDS-free gemm REGRESSED 255us: B re-read from
// L2 per wave with no sharing = 1.6TB L2 traffic + latency serialization at
// 48 VGPR. LDS staging was right; R6's problem was the [n][40] layout:
// 80B row stride -> all 64 lanes on banks = 0 mod 4 -> 8-way conflict on
// every fragment read = the 7.6M SQ_LDS_BANK_CONFLICT):
//  - gemm1/gemm2 back to LDS staging with FRAGMENT-LINEAR layouts:
//    fragment nt stored as contiguous 1024B, slot = quad*16+l16 (reading
//    lane id). Fragment reads = contiguous wave b128 (8-clock floor, zero
//    excess conflicts). B staged via slot order d = t+256j (contiguous
//    writes); A staged per-row (minor 8-way on its 1 write/k-step).
//    Same barriers, same MFMA order -> bit-identical numerics.
//  - edge path / spmm bodies: verified R8 exactly.

typedef __bf16 bf16;
typedef __bf16 bf16x8 __attribute__((ext_vector_type(8)));
typedef float floatx4 __attribute__((ext_vector_type(4)));
typedef float floatx2 __attribute__((ext_vector_type(2)));

#define NBMAX 400

// ---------------- weight conversion ----------------
__global__ __launch_bounds__(256) void conv_w(const float* __restrict__ W1,
                                              const float* __restrict__ W2,
                                              bf16* __restrict__ W1T,
                                              bf16* __restrict__ W2T) {
  int i = blockIdx.x * 256 + threadIdx.x;
  if (i < 512 * 256) {             // W1 [512][256] -> W1T [256][512]
    int k = i >> 8, n = i & 255;
    W1T[n * 512 + k] = (bf16)W1[i];
  }
  int j = i - 512 * 256;
  if (j >= 0 && j < 48 * 256) {    // W2 [256][40] -> W2T [48][256], pad rows 40..47
    int n = j >> 8, k = j & 255;
    W2T[j] = (n < 40) ? (bf16)W2[k * 40 + n] : (bf16)0.0f;
  }
}

// ---------------- partition stage 1: bucket histogram (persisted per block) ----
__global__ __launch_bounds__(256) void bhist_kernel(const int* __restrict__ er,
                                                    int* __restrict__ gbcount,
                                                    int* __restrict__ blkcnt,
                                                    int E, int NB, int EBLK) {
  __shared__ int cnt[NBMAX];
  const int t = threadIdx.x;
  for (int b = t; b < NB; b += 256) cnt[b] = 0;
  __syncthreads();
  const int base = blockIdx.x * 8192;
#pragma unroll
  for (int k = 0; k < 8; k++) {
    int i = base + k * 1024 + t * 4;
    if (i < E) {  // E % 4 == 0
      int4 r = *(const int4*)(er + i);
      atomicAdd(&cnt[r.x >> 8], 1);
      atomicAdd(&cnt[r.y >> 8], 1);
      atomicAdd(&cnt[r.z >> 8], 1);
      atomicAdd(&cnt[r.w >> 8], 1);
    }
  }
  __syncthreads();
  for (int b = t; b < NB; b += 256) {
    int c = cnt[b];
    blkcnt[b * EBLK + blockIdx.x] = c;
    if (c) atomicAdd(&gbcount[b], c);
  }
}

// ---------------- partition stage 2: bucket scan (1 block, 512 thr) ----------------
__global__ __launch_bounds__(512) void bscan_kernel(const int* __restrict__ gbcount,
                                                    int* __restrict__ bstart, int NB) {
  __shared__ int wsum[8];
  const int t = threadIdx.x;
  const int lane = t & 63, wave = t >> 6;
  int v = (t < NB) ? gbcount[t] : 0;
  int incl = v;
#pragma unroll
  for (int d = 1; d < 64; d <<= 1) {
    int o = __shfl_up(incl, d, 64);
    if (lane >= d) incl += o;
  }
  if (lane == 63) wsum[wave] = incl;
  __syncthreads();
  int off = 0;
#pragma unroll
  for (int w = 0; w < 8; w++)
    if (w < wave) off += wsum[w];
  int excl = off + incl - v;
  if (t <= NB) bstart[t] = excl;   // bstart[NB] = E
}

// ---------------- partition stage 2b: per-bucket cross-block scan ----------------
// block b: blkoff[b*EBLK + j] = bstart[b] + sum(blkcnt[b*EBLK + 0..j-1])
__global__ __launch_bounds__(512) void bscan2_kernel(const int* __restrict__ blkcnt,
                                                     const int* __restrict__ bstart,
                                                     int* __restrict__ blkoff, int EBLK) {
  __shared__ int wsum[8];
  const int b = blockIdx.x, t = threadIdx.x;
  const int lane = t & 63, wave = t >> 6;
  int v = (t < EBLK) ? blkcnt[b * EBLK + t] : 0;
  int incl = v;
#pragma unroll
  for (int d = 1; d < 64; d <<= 1) {
    int o = __shfl_up(incl, d, 64);
    if (lane >= d) incl += o;
  }
  if (lane == 63) wsum[wave] = incl;
  __syncthreads();
  int off = 0;
#pragma unroll
  for (int w = 0; w < 8; w++)
    if (w < wave) off += wsum[w];
  if (t < EBLK) blkoff[b * EBLK + t] = bstart[b] + off + incl - v;
}

// ---------------- partition stage 3: scatter into buckets ----------------
// epack_b[i] = ( (row&255)<<17 | col , val )
__global__ __launch_bounds__(256) void partA_kernel(
    const int* __restrict__ er, const int* __restrict__ ec, const float* __restrict__ ev,
    const int* __restrict__ blkoff, int2* __restrict__ epack_b, int E, int NB, int EBLK) {
  __shared__ int cur[NBMAX];
  const int t = threadIdx.x;
  for (int b = t; b < NB; b += 256) cur[b] = blkoff[b * EBLK + blockIdx.x];
  __syncthreads();
  const int base = blockIdx.x * 8192;
#pragma unroll
  for (int k = 0; k < 8; k++) {
    int i = base + k * 1024 + t * 4;
    if (i < E) {
      int4 r = *(const int4*)(er + i);
      int4 c = *(const int4*)(ec + i);
      float4 v = *(const float4*)(ev + i);
      int s0 = atomicAdd(&cur[r.x >> 8], 1);
      epack_b[s0] = make_int2(((r.x & 255) << 17) | c.x, __float_as_int(v.x));
      int s1 = atomicAdd(&cur[r.y >> 8], 1);
      epack_b[s1] = make_int2(((r.y & 255) << 17) | c.y, __float_as_int(v.y));
      int s2 = atomicAdd(&cur[r.z >> 8], 1);
      epack_b[s2] = make_int2(((r.z & 255) << 17) | c.z, __float_as_int(v.z));
      int s3 = atomicAdd(&cur[r.w >> 8], 1);
      epack_b[s3] = make_int2(((r.w & 255) << 17) | c.w, __float_as_int(v.w));
    }
  }
}

// ---------------- partition stage 4: per-bucket CSR finalize ----------------
__global__ __launch_bounds__(256) void partB_kernel(
    const int2* __restrict__ epack_b, const int* __restrict__ bstart,
    int2* __restrict__ epack_f, int* __restrict__ rp, int M) {
  __shared__ int rcnt[256];
  __shared__ int rcur[256];
  __shared__ int wsum[4];
  const int b = blockIdx.x, t = threadIdx.x;
  const int s = bstart[b];
  const int e_ = bstart[b + 1];
  rcnt[t] = 0;
  __syncthreads();
  for (int i = s + t; i < e_; i += 256) {
    unsigned int ro = ((unsigned int)epack_b[i].x) >> 17;
    atomicAdd(&rcnt[ro], 1);
  }
  __syncthreads();
  const int lane = t & 63, wave = t >> 6;
  int v = rcnt[t];
  int incl = v;
#pragma unroll
  for (int d = 1; d < 64; d <<= 1) {
    int o = __shfl_up(incl, d, 64);
    if (lane >= d) incl += o;
  }
  if (lane == 63) wsum[wave] = incl;
  __syncthreads();
  int off = 0;
#pragma unroll
  for (int w = 0; w < 4; w++)
    if (w < wave) off += wsum[w];
  rcur[t] = s + off + incl - v;
  __syncthreads();
  for (int i = s + t; i < e_; i += 256) {
    int2 m = epack_b[i];
    unsigned int ro = ((unsigned int)m.x) >> 17;
    int slot = atomicAdd(&rcur[ro], 1);
    epack_f[slot] = make_int2(m.x & 0x1FFFF, m.y);
  }
  __syncthreads();
  int r = (b << 8) + t;
  if (r < M) rp[r] = rcur[t];  // end of row r
}

// ---------------- GEMM1: T1f8 = fp8(x @ W1), fragment-linear LDS ----------------
// T1f8 layout: uint i of row n packs features {i, i+64, i+128, i+192} (e4m3).
// LDS: fragment nt = contiguous 1024B, slot = quad*16+l16 (= reading lane).
//   Asf[wave*512 + lane*8]  (4 frags, 4KB)   Bsf[nt*512 + lane*8] (16 frags, 16KB)
__global__ __launch_bounds__(256) void gemm1_kernel(const float* __restrict__ x,
                                                    const bf16* __restrict__ W1T,
                                                    unsigned int* __restrict__ T1f8, int M) {
  __shared__ __align__(16) bf16 Asf[4 * 512];
  __shared__ __align__(16) bf16 Bsf[16 * 512];
  const int t = threadIdx.x;
  const int wave = t >> 6, lane = t & 63;
  const int quad = lane >> 4, l16 = lane & 15;
  const int m0 = blockIdx.x * 64;
  floatx4 acc[16] = {};

  const int ar = t >> 2, aq = t & 3;
  const int a_gr = m0 + ar;
  const float* a_src = x + (size_t)a_gr * 512 + aq * 8;

  for (int k0 = 0; k0 < 512; k0 += 32) {
    __syncthreads();
    {  // A: thread t stages row ar, k-quad aq -> slot aq*16+(ar&15) of frag ar>>4
      float4 f0 = {0,0,0,0}, f1 = {0,0,0,0};
      if (a_gr < M) {
        const float4* p = (const float4*)(a_src + k0);
        f0 = p[0]; f1 = p[1];
      }
      bf16x8 av;
      av[0] = (bf16)f0.x; av[1] = (bf16)f0.y; av[2] = (bf16)f0.z; av[3] = (bf16)f0.w;
      av[4] = (bf16)f1.x; av[5] = (bf16)f1.y; av[6] = (bf16)f1.z; av[7] = (bf16)f1.w;
      *(bf16x8*)&Asf[(ar >> 4) * 512 + (aq * 16 + (ar & 15)) * 8] = av;
    }
#pragma unroll
    for (int j = 0; j < 4; j++) {  // B: thread t stages slots d=t+256j (contig writes)
      int d = t + 256 * j;
      int ntd = d >> 6, l16d = d & 15, qd = (d >> 4) & 3;
      bf16x8 bv = *(const bf16x8*)(W1T + (size_t)(ntd * 16 + l16d) * 512 + k0 + qd * 8);
      *(bf16x8*)&Bsf[d * 8] = bv;
    }
    __syncthreads();
    bf16x8 a = *(const bf16x8*)&Asf[wave * 512 + lane * 8];
#pragma unroll
    for (int nt = 0; nt < 16; nt++) {
      bf16x8 b = *(const bf16x8*)&Bsf[nt * 512 + lane * 8];
      acc[nt] = __builtin_amdgcn_mfma_f32_16x16x32_bf16(a, b, acc[nt], 0, 0, 0);
    }
  }
  const int row_base = m0 + wave * 16 + quad * 4;
#pragma unroll
  for (int nt0 = 0; nt0 < 4; nt0++) {
#pragma unroll
    for (int j = 0; j < 4; j++) {
      int gr = row_base + j;
      if (gr < M) {
        int p = 0;
        p = __builtin_amdgcn_cvt_pk_fp8_f32(acc[nt0][j],     acc[nt0 + 4][j],  p, false);
        p = __builtin_amdgcn_cvt_pk_fp8_f32(acc[nt0 + 8][j], acc[nt0 + 12][j], p, true);
        T1f8[(size_t)gr * 64 + nt0 * 16 + l16] = (unsigned int)p;
      }
    }
  }
}

// ---------------- SpMM1: mid = relu(gather-sum(T1f8) + b1) ----------------
// lane reads uint `lane` of each gathered row -> features {lane, lane+64,
// lane+128, lane+192}. 16 edges in flight per wave-iter (R8 body).
__global__ __launch_bounds__(256, 6) void spmm1_kernel(
    const int* __restrict__ rp, const int2* __restrict__ epack,
    const unsigned int* __restrict__ T1f8, const float* __restrict__ b1,
    float* __restrict__ mid, int M) {
  const int lane = threadIdx.x & 63;
  const int r = blockIdx.x * 4 + (threadIdx.x >> 6);
  if (r >= M) return;
  const int eend = rp[r];
  int e = (r == 0) ? 0 : rp[r - 1];
  float a0 = 0.f, a1 = 0.f, a2 = 0.f, a3 = 0.f;
  if (e < eend && (e & 1)) {  // align to even for int4 loads
    int2 m = epack[e];
    float v = __int_as_float(m.y);
    unsigned int u = T1f8[(((unsigned)m.x) << 6) | lane];
    floatx2 lo = __builtin_amdgcn_cvt_pk_f32_fp8(u, false);
    floatx2 hi = __builtin_amdgcn_cvt_pk_f32_fp8(u, true);
    a0 += v * lo[0]; a1 += v * lo[1]; a2 += v * hi[0]; a3 += v * hi[1];
    e++;
  }
  // ---- main: 16 edges in flight ----
  for (; e + 15 < eend; e += 16) {
    int4 pA = *(const int4*)(epack + e);
    int4 pB = *(const int4*)(epack + e + 2);
    int4 pC = *(const int4*)(epack + e + 4);
    int4 pD = *(const int4*)(epack + e + 6);
    int4 pE = *(const int4*)(epack + e + 8);
    int4 pF = *(const int4*)(epack + e + 10);
    int4 pG = *(const int4*)(epack + e + 12);
    int4 pH = *(const int4*)(epack + e + 14);
    unsigned int u0  = T1f8[(((unsigned)pA.x) << 6) | lane];
    unsigned int u1  = T1f8[(((unsigned)pA.z) << 6) | lane];
    unsigned int u2  = T1f8[(((unsigned)pB.x) << 6) | lane];
    unsigned int u3  = T1f8[(((unsigned)pB.z) << 6) | lane];
    unsigned int u4  = T1f8[(((unsigned)pC.x) << 6) | lane];
    unsigned int u5  = T1f8[(((unsigned)pC.z) << 6) | lane];
    unsigned int u6  = T1f8[(((unsigned)pD.x) << 6) | lane];
    unsigned int u7  = T1f8[(((unsigned)pD.z) << 6) | lane];
    unsigned int u8  = T1f8[(((unsigned)pE.x) << 6) | lane];
    unsigned int u9  = T1f8[(((unsigned)pE.z) << 6) | lane];
    unsigned int u10 = T1f8[(((unsigned)pF.x) << 6) | lane];
    unsigned int u11 = T1f8[(((unsigned)pF.z) << 6) | lane];
    unsigned int u12 = T1f8[(((unsigned)pG.x) << 6) | lane];
    unsigned int u13 = T1f8[(((unsigned)pG.z) << 6) | lane];
    unsigned int u14 = T1f8[(((unsigned)pH.x) << 6) | lane];
    unsigned int u15 = T1f8[(((unsigned)pH.z) << 6) | lane];
    float v0  = __int_as_float(pA.y), v1  = __int_as_float(pA.w);
    float v2  = __int_as_float(pB.y), v3  = __int_as_float(pB.w);
    float v4  = __int_as_float(pC.y), v5  = __int_as_float(pC.w);
    float v6  = __int_as_float(pD.y), v7  = __int_as_float(pD.w);
    float v8  = __int_as_float(pE.y), v9  = __int_as_float(pE.w);
    float v10 = __int_as_float(pF.y), v11 = __int_as_float(pF.w);
    float v12 = __int_as_float(pG.y), v13 = __int_as_float(pG.w);
    float v14 = __int_as_float(pH.y), v15 = __int_as_float(pH.w);
    floatx2 lo, hi;
    lo = __builtin_amdgcn_cvt_pk_f32_fp8(u0, false);
    hi = __builtin_amdgcn_cvt_pk_f32_fp8(u0, true);
    a0 += v0 * lo[0]; a1 += v0 * lo[1]; a2 += v0 * hi[0]; a3 += v0 * hi[1];
    lo = __builtin_amdgcn_cvt_pk_f32_fp8(u1, false);
    hi = __builtin_amdgcn_cvt_pk_f32_fp8(u1, true);
    a0 += v1 * lo[0]; a1 += v1 * lo[1]; a2 += v1 * hi[0]; a3 += v1 * hi[1];
    lo = __builtin_amdgcn_cvt_pk_f32_fp8(u2, false);
    hi = __builtin_amdgcn_cvt_pk_f32_fp8(u2, true);
    a0 += v2 * lo[0]; a1 += v2 * lo[1]; a2 += v2 * hi[0]; a3 += v2 * hi[1];
    lo = __builtin_amdgcn_cvt_pk_f32_fp8(u3, false);
    hi = __builtin_amdgcn_cvt_pk_f32_fp8(u3, true);
    a0 += v3 * lo[0]; a1 += v3 * lo[1]; a2 += v3 * hi[0]; a3 += v3 * hi[1];
    lo = __builtin_amdgcn_cvt_pk_f32_fp8(u4, false);
    hi = __builtin_amdgcn_cvt_pk_f32_fp8(u4, true);
    a0 += v4 * lo[0]; a1 += v4 * lo[1]; a2 += v4 * hi[0]; a3 += v4 * hi[1];
    lo = __builtin_amdgcn_cvt_pk_f32_fp8(u5, false);
    hi = __builtin_amdgcn_cvt_pk_f32_fp8(u5, true);
    a0 += v5 * lo[0]; a1 += v5 * lo[1]; a2 += v5 * hi[0]; a3 += v5 * hi[1];
    lo = __builtin_amdgcn_cvt_pk_f32_fp8(u6, false);
    hi = __builtin_amdgcn_cvt_pk_f32_fp8(u6, true);
    a0 += v6 * lo[0]; a1 += v6 * lo[1]; a2 += v6 * hi[0]; a3 += v6 * hi[1];
    lo = __builtin_amdgcn_cvt_pk_f32_fp8(u7, false);
    hi = __builtin_amdgcn_cvt_pk_f32_fp8(u7, true);
    a0 += v7 * lo[0]; a1 += v7 * lo[1]; a2 += v7 * hi[0]; a3 += v7 * hi[1];
    lo = __builtin_amdgcn_cvt_pk_f32_fp8(u8, false);
    hi = __builtin_amdgcn_cvt_pk_f32_fp8(u8, true);
    a0 += v8 * lo[0]; a1 += v8 * lo[1]; a2 += v8 * hi[0]; a3 += v8 * hi[1];
    lo = __builtin_amdgcn_cvt_pk_f32_fp8(u9, false);
    hi = __builtin_amdgcn_cvt_pk_f32_fp8(u9, true);
    a0 += v9 * lo[0]; a1 += v9 * lo[1]; a2 += v9 * hi[0]; a3 += v9 * hi[1];
    lo = __builtin_amdgcn_cvt_pk_f32_fp8(u10, false);
    hi = __builtin_amdgcn_cvt_pk_f32_fp8(u10, true);
    a0 += v10 * lo[0]; a1 += v10 * lo[1]; a2 += v10 * hi[0]; a3 += v10 * hi[1];
    lo = __builtin_amdgcn_cvt_pk_f32_fp8(u11, false);
    hi = __builtin_amdgcn_cvt_pk_f32_fp8(u11, true);
    a0 += v11 * lo[0]; a1 += v11 * lo[1]; a2 += v11 * hi[0]; a3 += v11 * hi[1];
    lo = __builtin_amdgcn_cvt_pk_f32_fp8(u12, false);
    hi = __builtin_amdgcn_cvt_pk_f32_fp8(u12, true);
    a0 += v12 * lo[0]; a1 += v12 * lo[1]; a2 += v12 * hi[0]; a3 += v12 * hi[1];
    lo = __builtin_amdgcn_cvt_pk_f32_fp8(u13, false);
    hi = __builtin_amdgcn_cvt_pk_f32_fp8(u13, true);
    a0 += v13 * lo[0]; a1 += v13 * lo[1]; a2 += v13 * hi[0]; a3 += v13 * hi[1];
    lo = __builtin_amdgcn_cvt_pk_f32_fp8(u14, false);
    hi = __builtin_amdgcn_cvt_pk_f32_fp8(u14, true);
    a0 += v14 * lo[0]; a1 += v14 * lo[1]; a2 += v14 * hi[0]; a3 += v14 * hi[1];
    lo = __builtin_amdgcn_cvt_pk_f32_fp8(u15, false);
    hi = __builtin_amdgcn_cvt_pk_f32_fp8(u15, true);
    a0 += v15 * lo[0]; a1 += v15 * lo[1]; a2 += v15 * hi[0]; a3 += v15 * hi[1];
  }
  // ---- 8-edge tail ----
  for (; e + 7 < eend; e += 8) {
    int4 p01 = *(const int4*)(epack + e);
    int4 p23 = *(const int4*)(epack + e + 2);
    int4 p45 = *(const int4*)(epack + e + 4);
    int4 p67 = *(const int4*)(epack + e + 6);
    unsigned int u0 = T1f8[(((unsigned)p01.x) << 6) | lane];
    unsigned int u1 = T1f8[(((unsigned)p01.z) << 6) | lane];
    unsigned int u2 = T1f8[(((unsigned)p23.x) << 6) | lane];
    unsigned int u3 = T1f8[(((unsigned)p23.z) << 6) | lane];
    unsigned int u4 = T1f8[(((unsigned)p45.x) << 6) | lane];
    unsigned int u5 = T1f8[(((unsigned)p45.z) << 6) | lane];
    unsigned int u6 = T1f8[(((unsigned)p67.x) << 6) | lane];
    unsigned int u7 = T1f8[(((unsigned)p67.z) << 6) | lane];
    float v0 = __int_as_float(p01.y), v1 = __int_as_float(p01.w);
    float v2 = __int_as_float(p23.y), v3 = __int_as_float(p23.w);
    float v4 = __int_as_float(p45.y), v5 = __int_as_float(p45.w);
    float v6 = __int_as_float(p67.y), v7 = __int_as_float(p67.w);
    floatx2 lo, hi;
    lo = __builtin_amdgcn_cvt_pk_f32_fp8(u0, false);
    hi = __builtin_amdgcn_cvt_pk_f32_fp8(u0, true);
    a0 += v0 * lo[0]; a1 += v0 * lo[1]; a2 += v0 * hi[0]; a3 += v0 * hi[1];
    lo = __builtin_amdgcn_cvt_pk_f32_fp8(u1, false);
    hi = __builtin_amdgcn_cvt_pk_f32_fp8(u1, true);
    a0 += v1 * lo[0]; a1 += v1 * lo[1]; a2 += v1 * hi[0]; a3 += v1 * hi[1];
    lo = __builtin_amdgcn_cvt_pk_f32_fp8(u2, false);
    hi = __builtin_amdgcn_cvt_pk_f32_fp8(u2, true);
    a0 += v2 * lo[0]; a1 += v2 * lo[1]; a2 += v2 * hi[0]; a3 += v2 * hi[1];
    lo = __builtin_amdgcn_cvt_pk_f32_fp8(u3, false);
    hi = __builtin_amdgcn_cvt_pk_f32_fp8(u3, true);
    a0 += v3 * lo[0]; a1 += v3 * lo[1]; a2 += v3 * hi[0]; a3 += v3 * hi[1];
    lo = __builtin_amdgcn_cvt_pk_f32_fp8(u4, false);
    hi = __builtin_amdgcn_cvt_pk_f32_fp8(u4, true);
    a0 += v4 * lo[0]; a1 += v4 * lo[1]; a2 += v4 * hi[0]; a3 += v4 * hi[1];
    lo = __builtin_amdgcn_cvt_pk_f32_fp8(u5, false);
    hi = __builtin_amdgcn_cvt_pk_f32_fp8(u5, true);
    a0 += v5 * lo[0]; a1 += v5 * lo[1]; a2 += v5 * hi[0]; a3 += v5 * hi[1];
    lo = __builtin_amdgcn_cvt_pk_f32_fp8(u6, false);
    hi = __builtin_amdgcn_cvt_pk_f32_fp8(u6, true);
    a0 += v6 * lo[0]; a1 += v6 * lo[1]; a2 += v6 * hi[0]; a3 += v6 * hi[1];
    lo = __builtin_amdgcn_cvt_pk_f32_fp8(u7, false);
    hi = __builtin_amdgcn_cvt_pk_f32_fp8(u7, true);
    a0 += v7 * lo[0]; a1 += v7 * lo[1]; a2 += v7 * hi[0]; a3 += v7 * hi[1];
  }
  for (; e + 3 < eend; e += 4) {
    int4 p01 = *(const int4*)(epack + e);
    int4 p23 = *(const int4*)(epack + e + 2);
    unsigned int u0 = T1f8[(((unsigned)p01.x) << 6) | lane];
    unsigned int u1 = T1f8[(((unsigned)p01.z) << 6) | lane];
    unsigned int u2 = T1f8[(((unsigned)p23.x) << 6) | lane];
    unsigned int u3 = T1f8[(((unsigned)p23.z) << 6) | lane];
    float v0 = __int_as_float(p01.y), v1 = __int_as_float(p01.w);
    float v2 = __int_as_float(p23.y), v3 = __int_as_float(p23.w);
    floatx2 lo, hi;
    lo = __builtin_amdgcn_cvt_pk_f32_fp8(u0, false);
    hi = __builtin_amdgcn_cvt_pk_f32_fp8(u0, true);
    a0 += v0 * lo[0]; a1 += v0 * lo[1]; a2 += v0 * hi[0]; a3 += v0 * hi[1];
    lo = __builtin_amdgcn_cvt_pk_f32_fp8(u1, false);
    hi = __builtin_amdgcn_cvt_pk_f32_fp8(u1, true);
    a0 += v1 * lo[0]; a1 += v1 * lo[1]; a2 += v1 * hi[0]; a3 += v1 * hi[1];
    lo = __builtin_amdgcn_cvt_pk_f32_fp8(u2, false);
    hi = __builtin_amdgcn_cvt_pk_f32_fp8(u2, true);
    a0 += v2 * lo[0]; a1 += v2 * lo[1]; a2 += v2 * hi[0]; a3 += v2 * hi[1];
    lo = __builtin_amdgcn_cvt_pk_f32_fp8(u3, false);
    hi = __builtin_amdgcn_cvt_pk_f32_fp8(u3, true);
    a0 += v3 * lo[0]; a1 += v3 * lo[1]; a2 += v3 * hi[0]; a3 += v3 * hi[1];
  }
  for (; e < eend; e++) {
    int2 m = epack[e];
    float v = __int_as_float(m.y);
    unsigned int u = T1f8[(((unsigned)m.x) << 6) | lane];
    floatx2 lo = __builtin_amdgcn_cvt_pk_f32_fp8(u, false);
    floatx2 hi = __builtin_amdgcn_cvt_pk_f32_fp8(u, true);
    a0 += v * lo[0]; a1 += v * lo[1]; a2 += v * hi[0]; a3 += v * hi[1];
  }
  // a0..a3 are features lane, lane+64, lane+128, lane+192
  float o0 = fmaxf(a0 + b1[lane],       0.f);
  float o1 = fmaxf(a1 + b1[lane + 64],  0.f);
  float o2 = fmaxf(a2 + b1[lane + 128], 0.f);
  float o3 = fmaxf(a3 + b1[lane + 192], 0.f);
  float* mrow = mid + (size_t)r * 256 + lane;
  mrow[0]   = o0;
  mrow[64]  = o1;
  mrow[128] = o2;
  mrow[192] = o3;
}

// ---------------- GEMM2: T2f8 = fp8(mid @ W2), fragment-linear LDS ----------------
// T2f8 layout: uint i of row n packs cols {i, i+16, i+32} (byte3 = 0).
__global__ __launch_bounds__(256) void gemm2_kernel(const float* __restrict__ mid,
                                                    const bf16* __restrict__ W2T,
                                                    unsigned int* __restrict__ T2f8, int M) {
  __shared__ __align__(16) bf16 Asf[4 * 512];   // 4KB
  __shared__ __align__(16) bf16 Bsf[3 * 512];   // 3KB
  const int t = threadIdx.x;
  const int wave = t >> 6, lane = t & 63;
  const int quad = lane >> 4, l16 = lane & 15;
  const int m0 = blockIdx.x * 64;
  floatx4 acc[3] = {};
  const int ar = t >> 2, aq = t & 3;
  const int a_gr = m0 + ar;
  const float* a_src = mid + (size_t)a_gr * 256 + aq * 8;

  for (int k0 = 0; k0 < 256; k0 += 32) {
    __syncthreads();
    {
      float4 f0 = {0,0,0,0}, f1 = {0,0,0,0};
      if (a_gr < M) {
        const float4* p = (const float4*)(a_src + k0);
        f0 = p[0]; f1 = p[1];
      }
      bf16x8 av;
      av[0] = (bf16)f0.x; av[1] = (bf16)f0.y; av[2] = (bf16)f0.z; av[3] = (bf16)f0.w;
      av[4] = (bf16)f1.x; av[5] = (bf16)f1.y; av[6] = (bf16)f1.z; av[7] = (bf16)f1.w;
      *(bf16x8*)&Asf[(ar >> 4) * 512 + (aq * 16 + (ar & 15)) * 8] = av;
    }
    if (t < 192) {  // B: thread t stages slot t (contig writes)
      int ntd = t >> 6, l16d = t & 15, qd = (t >> 4) & 3;
      bf16x8 bv = *(const bf16x8*)(W2T + (size_t)(ntd * 16 + l16d) * 256 + k0 + qd * 8);
      *(bf16x8*)&Bsf[t * 8] = bv;
    }
    __syncthreads();
    bf16x8 a = *(const bf16x8*)&Asf[wave * 512 + lane * 8];
#pragma unroll
    for (int nt = 0; nt < 3; nt++) {
      bf16x8 b = *(const bf16x8*)&Bsf[nt * 512 + lane * 8];
      acc[nt] = __builtin_amdgcn_mfma_f32_16x16x32_bf16(a, b, acc[nt], 0, 0, 0);
    }
  }
  const int row_base = m0 + wave * 16 + quad * 4;
#pragma unroll
  for (int j = 0; j < 4; j++) {
    int gr = row_base + j;
    if (gr < M) {
      int p = 0;
      p = __builtin_amdgcn_cvt_pk_fp8_f32(acc[0][j], acc[1][j], p, false);
      p = __builtin_amdgcn_cvt_pk_fp8_f32(acc[2][j], 0.0f,      p, true);
      T2f8[(size_t)gr * 16 + l16] = (unsigned int)p;
    }
  }
}

// ---------------- SpMM2: out = gather-sum(T2f8) + b2 ----------------
// quarter-wave (16 lanes) per edge; 16 edges per wave-iter (4/group);
// lane q reads uint q -> cols {q, q+16, q+32}. shfl-tree combine.
__global__ __launch_bounds__(256, 6) void spmm2_kernel(
    const int* __restrict__ rp, const int2* __restrict__ epack,
    const unsigned int* __restrict__ T2f8, const float* __restrict__ b2,
    float* __restrict__ out2, int M) {
  const int lane = threadIdx.x & 63;
  const int r = blockIdx.x * 4 + (threadIdx.x >> 6);
  if (r >= M) return;
  const int q = lane & 15;
  const int g = lane >> 4;  // edge group 0..3
  const int eend = rp[r];
  int e = (r == 0) ? 0 : rp[r - 1];
  float a0 = 0.f, a1 = 0.f, a2 = 0.f;
  if (e < eend && (e & 1)) {  // align to even for int4 loads (group 0 takes it)
    if (g == 0) {
      int2 m = epack[e];
      float v = __int_as_float(m.y);
      unsigned int u = T2f8[(((unsigned)m.x) << 4) | q];
      floatx2 lo = __builtin_amdgcn_cvt_pk_f32_fp8(u, false);
      floatx2 hi = __builtin_amdgcn_cvt_pk_f32_fp8(u, true);
      a0 += v * lo[0]; a1 += v * lo[1]; a2 += v * hi[0];
    }
    e++;
  }
  // ---- main: 16 edges / wave-iter, group g: e+2g,e+2g+1,e+8+2g,e+8+2g+1 ----
  for (; e + 15 < eend; e += 16) {
    int4 m0 = *(const int4*)(epack + e + 2 * g);
    int4 m1 = *(const int4*)(epack + e + 8 + 2 * g);
    unsigned int u0 = T2f8[(((unsigned)m0.x) << 4) | q];
    unsigned int u1 = T2f8[(((unsigned)m0.z) << 4) | q];
    unsigned int u2 = T2f8[(((unsigned)m1.x) << 4) | q];
    unsigned int u3 = T2f8[(((unsigned)m1.z) << 4) | q];
    float v0 = __int_as_float(m0.y), v1 = __int_as_float(m0.w);
    float v2 = __int_as_float(m1.y), v3 = __int_as_float(m1.w);
    floatx2 lo, hi;
    lo = __builtin_amdgcn_cvt_pk_f32_fp8(u0, false);
    hi = __builtin_amdgcn_cvt_pk_f32_fp8(u0, true);
    a0 += v0 * lo[0]; a1 += v0 * lo[1]; a2 += v0 * hi[0];
    lo = __builtin_amdgcn_cvt_pk_f32_fp8(u1, false);
    hi = __builtin_amdgcn_cvt_pk_f32_fp8(u1, true);
    a0 += v1 * lo[0]; a1 += v1 * lo[1]; a2 += v1 * hi[0];
    lo = __builtin_amdgcn_cvt_pk_f32_fp8(u2, false);
    hi = __builtin_amdgcn_cvt_pk_f32_fp8(u2, true);
    a0 += v2 * lo[0]; a1 += v2 * lo[1]; a2 += v2 * hi[0];
    lo = __builtin_amdgcn_cvt_pk_f32_fp8(u3, false);
    hi = __builtin_amdgcn_cvt_pk_f32_fp8(u3, true);
    a0 += v3 * lo[0]; a1 += v3 * lo[1]; a2 += v3 * hi[0];
  }
  for (; e + 7 < eend; e += 8) {  // group g: edges e+2g, e+2g+1 via one int4
    int4 m = *(const int4*)(epack + e + 2 * g);
    float v0 = __int_as_float(m.y), v1 = __int_as_float(m.w);
    unsigned int u0 = T2f8[(((unsigned)m.x) << 4) | q];
    unsigned int u1 = T2f8[(((unsigned)m.z) << 4) | q];
    floatx2 l0 = __builtin_amdgcn_cvt_pk_f32_fp8(u0, false);
    floatx2 h0 = __builtin_amdgcn_cvt_pk_f32_fp8(u0, true);
    floatx2 l1 = __builtin_amdgcn_cvt_pk_f32_fp8(u1, false);
    floatx2 h1 = __builtin_amdgcn_cvt_pk_f32_fp8(u1, true);
    a0 += v0 * l0[0]; a1 += v0 * l0[1]; a2 += v0 * h0[0];
    a0 += v1 * l1[0]; a1 += v1 * l1[1]; a2 += v1 * h1[0];
  }
  for (; e + 3 < eend; e += 4) {  // group g: edge e+g
    int2 m = epack[e + g];
    float v = __int_as_float(m.y);
    unsigned int u = T2f8[(((unsigned)m.x) << 4) | q];
    floatx2 lo = __builtin_amdgcn_cvt_pk_f32_fp8(u, false);
    floatx2 hi = __builtin_amdgcn_cvt_pk_f32_fp8(u, true);
    a0 += v * lo[0]; a1 += v * lo[1]; a2 += v * hi[0];
  }
  if (e + g < eend) {  // tail: groups 0..(eend-e-1)
    int2 m = epack[e + g];
    float v = __int_as_float(m.y);
    unsigned int u = T2f8[(((unsigned)m.x) << 4) | q];
    floatx2 lo = __builtin_amdgcn_cvt_pk_f32_fp8(u, false);
    floatx2 hi = __builtin_amdgcn_cvt_pk_f32_fp8(u, true);
    a0 += v * lo[0]; a1 += v * lo[1]; a2 += v * hi[0];
  }
  a0 += __shfl_down(a0, 32, 64); a0 += __shfl_down(a0, 16, 64);
  a1 += __shfl_down(a1, 32, 64); a1 += __shfl_down(a1, 16, 64);
  a2 += __shfl_down(a2, 32, 64); a2 += __shfl_down(a2, 16, 64);
  if (lane < 16) {
    // a0..a2 are cols lane, lane+16, lane+32 (valid cols < 40)
    float* orow = out2 + (size_t)r * 40;
    orow[lane]      = a0 + b2[lane];
    orow[lane + 16] = a1 + b2[lane + 16];
    if (lane < 8) orow[lane + 32] = a2 + b2[lane + 32];
  }
}

// ---------------- launch ----------------
extern "C" void kernel_launch(void* const* d_in, const int* in_sizes, int n_in,
                              void* d_out, int out_size, void* d_ws, size_t ws_size,
                              hipStream_t stream) {
  const float* x        = (const float*)d_in[0];
  const int*   edge_row = (const int*)d_in[1];
  const int*   edge_col = (const int*)d_in[2];
  const float* edge_val = (const float*)d_in[3];
  const float* W1       = (const float*)d_in[4];
  const float* b1       = (const float*)d_in[5];
  const float* W2       = (const float*)d_in[6];
  const float* b2       = (const float*)d_in[7];
  const int M = in_sizes[0] / 512;  // 100000 nodes
  const int E = in_sizes[1];        // 3200000 edges
  const int NB = (M + 255) >> 8;    // 391 buckets
  const int EBLK = (E + 8191) / 8192;  // 391 blocks

  char* ws = (char*)d_ws;
  size_t off = 0;
  bf16* W1T     = (bf16*)(ws + off);  off += 512 * 256 * 2;
  bf16* W2T     = (bf16*)(ws + off);  off += 48 * 256 * 2;
  unsigned int* T1f8 = (unsigned int*)(ws + off); off += (size_t)M * 256;
  unsigned int* T2f8 = (unsigned int*)(ws + off); off += (size_t)M * 64;
  int* rp       = (int*)(ws + off);   off += (size_t)M * 4;
  int* gbcount  = (int*)(ws + off);   off += NBMAX * 4;
  int* bstart   = (int*)(ws + off);   off += (NBMAX + 1) * 4;
  int* blkcnt   = (int*)(ws + off);   off += (size_t)NB * EBLK * 4;
  int* blkoff   = (int*)(ws + off);   off += (size_t)NB * EBLK * 4;
  off = (off + 15) & ~(size_t)15;
  int2* epack_b = (int2*)(ws + off);  off += (size_t)E * 8;
  int2* epack_f = (int2*)(ws + off);  off += (size_t)E * 8;

  float* mid  = (float*)d_out;
  float* out2 = mid + (size_t)M * 256;

  hipMemsetAsync(gbcount, 0, NBMAX * 4, stream);
  conv_w<<<(512 * 256 + 48 * 256 + 255) / 256, 256, 0, stream>>>(W1, W2, W1T, W2T);
  bhist_kernel<<<EBLK, 256, 0, stream>>>(edge_row, gbcount, blkcnt, E, NB, EBLK);
  bscan_kernel<<<1, 512, 0, stream>>>(gbcount, bstart, NB);
  bscan2_kernel<<<NB, 512, 0, stream>>>(blkcnt, bstart, blkoff, EBLK);
  partA_kernel<<<EBLK, 256, 0, stream>>>(edge_row, edge_col, edge_val,
                                         blkoff, epack_b, E, NB, EBLK);
  partB_kernel<<<NB, 256, 0, stream>>>(epack_b, bstart, epack_f, rp, M);
  gemm1_kernel<<<(M + 63) / 64, 256, 0, stream>>>(x, W1T, T1f8, M);
  spmm1_kernel<<<(M + 3) / 4, 256, 0, stream>>>(rp, epack_f, T1f8, b1, mid, M);
  gemm2_kernel<<<(M + 63) / 64, 256, 0, stream>>>(mid, W2T, T2f8, M);
  spmm2_kernel<<<(M + 3) / 4, 256, 0, stream>>>(rp, epack_f, T2f8, b2, out2, M);
}

// Round 11
// 651.651 us; speedup vs baseline: 1.2399x; 1.0085x over previous
//
#include <hip/hip_runtime.h>

// GCN forward: mid = relu(spmm(A, x@W1) + b1); out = spmm(A, mid@W2) + b2
// N=100000, F=512, H=256, C=40, E=3.2M.
//
// R13 changes vs R12 (R12 = 657.2us, best; fragment-linear LDS removed gemm1
// conflicts but total unchanged -> gemm1 still ~115us = exposed-latency-bound:
// 16 serial k-steps of {barrier, HBM load, barrier, MFMA}):
//  - gemm1/gemm2: register double-buffer. Prefetch k+1's A (2xfloat4) and
//    B (4x bf16x8) into regs DURING k's MFMA section (sched_barrier(0) pins
//    the issue before MFMA - hipcc would otherwise sink loads to their
//    ds_write use, the R8/R11 lesson). ds_write staged regs at top of next
//    step. Same loads/offsets/MFMA order -> bit-identical numerics.
//    gemm1 is LDS/acc-limited, +24 VGPR crosses no occupancy step.
//  - everything else byte-identical to R12 (edge path = verified R8).

typedef __bf16 bf16;
typedef __bf16 bf16x8 __attribute__((ext_vector_type(8)));
typedef float floatx4 __attribute__((ext_vector_type(4)));
typedef float floatx2 __attribute__((ext_vector_type(2)));

#define NBMAX 400

// ---------------- weight conversion ----------------
__global__ __launch_bounds__(256) void conv_w(const float* __restrict__ W1,
                                              const float* __restrict__ W2,
                                              bf16* __restrict__ W1T,
                                              bf16* __restrict__ W2T) {
  int i = blockIdx.x * 256 + threadIdx.x;
  if (i < 512 * 256) {             // W1 [512][256] -> W1T [256][512]
    int k = i >> 8, n = i & 255;
    W1T[n * 512 + k] = (bf16)W1[i];
  }
  int j = i - 512 * 256;
  if (j >= 0 && j < 48 * 256) {    // W2 [256][40] -> W2T [48][256], pad rows 40..47
    int n = j >> 8, k = j & 255;
    W2T[j] = (n < 40) ? (bf16)W2[k * 40 + n] : (bf16)0.0f;
  }
}

// ---------------- partition stage 1: bucket histogram (persisted per block) ----
__global__ __launch_bounds__(256) void bhist_kernel(const int* __restrict__ er,
                                                    int* __restrict__ gbcount,
                                                    int* __restrict__ blkcnt,
                                                    int E, int NB, int EBLK) {
  __shared__ int cnt[NBMAX];
  const int t = threadIdx.x;
  for (int b = t; b < NB; b += 256) cnt[b] = 0;
  __syncthreads();
  const int base = blockIdx.x * 8192;
#pragma unroll
  for (int k = 0; k < 8; k++) {
    int i = base + k * 1024 + t * 4;
    if (i < E) {  // E % 4 == 0
      int4 r = *(const int4*)(er + i);
      atomicAdd(&cnt[r.x >> 8], 1);
      atomicAdd(&cnt[r.y >> 8], 1);
      atomicAdd(&cnt[r.z >> 8], 1);
      atomicAdd(&cnt[r.w >> 8], 1);
    }
  }
  __syncthreads();
  for (int b = t; b < NB; b += 256) {
    int c = cnt[b];
    blkcnt[b * EBLK + blockIdx.x] = c;
    if (c) atomicAdd(&gbcount[b], c);
  }
}

// ---------------- partition stage 2: bucket scan (1 block, 512 thr) ----------------
__global__ __launch_bounds__(512) void bscan_kernel(const int* __restrict__ gbcount,
                                                    int* __restrict__ bstart, int NB) {
  __shared__ int wsum[8];
  const int t = threadIdx.x;
  const int lane = t & 63, wave = t >> 6;
  int v = (t < NB) ? gbcount[t] : 0;
  int incl = v;
#pragma unroll
  for (int d = 1; d < 64; d <<= 1) {
    int o = __shfl_up(incl, d, 64);
    if (lane >= d) incl += o;
  }
  if (lane == 63) wsum[wave] = incl;
  __syncthreads();
  int off = 0;
#pragma unroll
  for (int w = 0; w < 8; w++)
    if (w < wave) off += wsum[w];
  int excl = off + incl - v;
  if (t <= NB) bstart[t] = excl;   // bstart[NB] = E
}

// ---------------- partition stage 2b: per-bucket cross-block scan ----------------
// block b: blkoff[b*EBLK + j] = bstart[b] + sum(blkcnt[b*EBLK + 0..j-1])
__global__ __launch_bounds__(512) void bscan2_kernel(const int* __restrict__ blkcnt,
                                                     const int* __restrict__ bstart,
                                                     int* __restrict__ blkoff, int EBLK) {
  __shared__ int wsum[8];
  const int b = blockIdx.x, t = threadIdx.x;
  const int lane = t & 63, wave = t >> 6;
  int v = (t < EBLK) ? blkcnt[b * EBLK + t] : 0;
  int incl = v;
#pragma unroll
  for (int d = 1; d < 64; d <<= 1) {
    int o = __shfl_up(incl, d, 64);
    if (lane >= d) incl += o;
  }
  if (lane == 63) wsum[wave] = incl;
  __syncthreads();
  int off = 0;
#pragma unroll
  for (int w = 0; w < 8; w++)
    if (w < wave) off += wsum[w];
  if (t < EBLK) blkoff[b * EBLK + t] = bstart[b] + off + incl - v;
}

// ---------------- partition stage 3: scatter into buckets ----------------
// epack_b[i] = ( (row&255)<<17 | col , val )
__global__ __launch_bounds__(256) void partA_kernel(
    const int* __restrict__ er, const int* __restrict__ ec, const float* __restrict__ ev,
    const int* __restrict__ blkoff, int2* __restrict__ epack_b, int E, int NB, int EBLK) {
  __shared__ int cur[NBMAX];
  const int t = threadIdx.x;
  for (int b = t; b < NB; b += 256) cur[b] = blkoff[b * EBLK + blockIdx.x];
  __syncthreads();
  const int base = blockIdx.x * 8192;
#pragma unroll
  for (int k = 0; k < 8; k++) {
    int i = base + k * 1024 + t * 4;
    if (i < E) {
      int4 r = *(const int4*)(er + i);
      int4 c = *(const int4*)(ec + i);
      float4 v = *(const float4*)(ev + i);
      int s0 = atomicAdd(&cur[r.x >> 8], 1);
      epack_b[s0] = make_int2(((r.x & 255) << 17) | c.x, __float_as_int(v.x));
      int s1 = atomicAdd(&cur[r.y >> 8], 1);
      epack_b[s1] = make_int2(((r.y & 255) << 17) | c.y, __float_as_int(v.y));
      int s2 = atomicAdd(&cur[r.z >> 8], 1);
      epack_b[s2] = make_int2(((r.z & 255) << 17) | c.z, __float_as_int(v.z));
      int s3 = atomicAdd(&cur[r.w >> 8], 1);
      epack_b[s3] = make_int2(((r.w & 255) << 17) | c.w, __float_as_int(v.w));
    }
  }
}

// ---------------- partition stage 4: per-bucket CSR finalize ----------------
__global__ __launch_bounds__(256) void partB_kernel(
    const int2* __restrict__ epack_b, const int* __restrict__ bstart,
    int2* __restrict__ epack_f, int* __restrict__ rp, int M) {
  __shared__ int rcnt[256];
  __shared__ int rcur[256];
  __shared__ int wsum[4];
  const int b = blockIdx.x, t = threadIdx.x;
  const int s = bstart[b];
  const int e_ = bstart[b + 1];
  rcnt[t] = 0;
  __syncthreads();
  for (int i = s + t; i < e_; i += 256) {
    unsigned int ro = ((unsigned int)epack_b[i].x) >> 17;
    atomicAdd(&rcnt[ro], 1);
  }
  __syncthreads();
  const int lane = t & 63, wave = t >> 6;
  int v = rcnt[t];
  int incl = v;
#pragma unroll
  for (int d = 1; d < 64; d <<= 1) {
    int o = __shfl_up(incl, d, 64);
    if (lane >= d) incl += o;
  }
  if (lane == 63) wsum[wave] = incl;
  __syncthreads();
  int off = 0;
#pragma unroll
  for (int w = 0; w < 4; w++)
    if (w < wave) off += wsum[w];
  rcur[t] = s + off + incl - v;
  __syncthreads();
  for (int i = s + t; i < e_; i += 256) {
    int2 m = epack_b[i];
    unsigned int ro = ((unsigned int)m.x) >> 17;
    int slot = atomicAdd(&rcur[ro], 1);
    epack_f[slot] = make_int2(m.x & 0x1FFFF, m.y);
  }
  __syncthreads();
  int r = (b << 8) + t;
  if (r < M) rp[r] = rcur[t];  // end of row r
}

// ---------------- GEMM1: T1f8 = fp8(x @ W1), frag-linear LDS + reg dbuf ----------------
// T1f8 layout: uint i of row n packs features {i, i+64, i+128, i+192} (e4m3).
// LDS: fragment nt = contiguous 1024B, slot = quad*16+l16 (= reading lane).
// Register double-buffer: k+1's A/B prefetched during k's MFMA section.
__global__ __launch_bounds__(256) void gemm1_kernel(const float* __restrict__ x,
                                                    const bf16* __restrict__ W1T,
                                                    unsigned int* __restrict__ T1f8, int M) {
  __shared__ __align__(16) bf16 Asf[4 * 512];
  __shared__ __align__(16) bf16 Bsf[16 * 512];
  const int t = threadIdx.x;
  const int wave = t >> 6, lane = t & 63;
  const int quad = lane >> 4, l16 = lane & 15;
  const int m0 = blockIdx.x * 64;
  floatx4 acc[16] = {};

  const int ar = t >> 2, aq = t & 3;
  const int a_gr = m0 + ar;
  const bool a_ok = (a_gr < M);
  const float* a_src = x + (size_t)a_gr * 512 + aq * 8;
  const int aslot = (ar >> 4) * 512 + (aq * 16 + (ar & 15)) * 8;
  // B source pointers for this thread's 4 staged slots (d = t + 256j)
  const bf16* bsrc0;
  const bf16* bsrc1;
  const bf16* bsrc2;
  const bf16* bsrc3;
  {
    int d0 = t, d1 = t + 256, d2 = t + 512, d3 = t + 768;
    bsrc0 = W1T + (size_t)((d0 >> 6) * 16 + (d0 & 15)) * 512 + ((d0 >> 4) & 3) * 8;
    bsrc1 = W1T + (size_t)((d1 >> 6) * 16 + (d1 & 15)) * 512 + ((d1 >> 4) & 3) * 8;
    bsrc2 = W1T + (size_t)((d2 >> 6) * 16 + (d2 & 15)) * 512 + ((d2 >> 4) & 3) * 8;
    bsrc3 = W1T + (size_t)((d3 >> 6) * 16 + (d3 & 15)) * 512 + ((d3 >> 4) & 3) * 8;
  }
  // prologue: prefetch k0 = 0
  float4 f0 = {0,0,0,0}, f1 = {0,0,0,0};
  if (a_ok) {
    const float4* p = (const float4*)a_src;
    f0 = p[0]; f1 = p[1];
  }
  bf16x8 bq0 = *(const bf16x8*)(bsrc0);
  bf16x8 bq1 = *(const bf16x8*)(bsrc1);
  bf16x8 bq2 = *(const bf16x8*)(bsrc2);
  bf16x8 bq3 = *(const bf16x8*)(bsrc3);

  for (int k0 = 0; k0 < 512; k0 += 32) {
    __syncthreads();
    {
      bf16x8 av;
      av[0] = (bf16)f0.x; av[1] = (bf16)f0.y; av[2] = (bf16)f0.z; av[3] = (bf16)f0.w;
      av[4] = (bf16)f1.x; av[5] = (bf16)f1.y; av[6] = (bf16)f1.z; av[7] = (bf16)f1.w;
      *(bf16x8*)&Asf[aslot] = av;
      *(bf16x8*)&Bsf[(size_t)t * 8]         = bq0;
      *(bf16x8*)&Bsf[(size_t)(t + 256) * 8] = bq1;
      *(bf16x8*)&Bsf[(size_t)(t + 512) * 8] = bq2;
      *(bf16x8*)&Bsf[(size_t)(t + 768) * 8] = bq3;
    }
    __syncthreads();
    if (k0 + 32 < 512) {  // prefetch next k-step; overlaps MFMA below
      f0 = make_float4(0.f, 0.f, 0.f, 0.f);
      f1 = make_float4(0.f, 0.f, 0.f, 0.f);
      if (a_ok) {
        const float4* p = (const float4*)(a_src + k0 + 32);
        f0 = p[0]; f1 = p[1];
      }
      bq0 = *(const bf16x8*)(bsrc0 + k0 + 32);
      bq1 = *(const bf16x8*)(bsrc1 + k0 + 32);
      bq2 = *(const bf16x8*)(bsrc2 + k0 + 32);
      bq3 = *(const bf16x8*)(bsrc3 + k0 + 32);
    }
    __builtin_amdgcn_sched_barrier(0);  // pin prefetch issue before MFMA section
    bf16x8 a = *(const bf16x8*)&Asf[wave * 512 + lane * 8];
#pragma unroll
    for (int nt = 0; nt < 16; nt++) {
      bf16x8 b = *(const bf16x8*)&Bsf[nt * 512 + lane * 8];
      acc[nt] = __builtin_amdgcn_mfma_f32_16x16x32_bf16(a, b, acc[nt], 0, 0, 0);
    }
  }
  const int row_base = m0 + wave * 16 + quad * 4;
#pragma unroll
  for (int nt0 = 0; nt0 < 4; nt0++) {
#pragma unroll
    for (int j = 0; j < 4; j++) {
      int gr = row_base + j;
      if (gr < M) {
        int p = 0;
        p = __builtin_amdgcn_cvt_pk_fp8_f32(acc[nt0][j],     acc[nt0 + 4][j],  p, false);
        p = __builtin_amdgcn_cvt_pk_fp8_f32(acc[nt0 + 8][j], acc[nt0 + 12][j], p, true);
        T1f8[(size_t)gr * 64 + nt0 * 16 + l16] = (unsigned int)p;
      }
    }
  }
}

// ---------------- SpMM1: mid = relu(gather-sum(T1f8) + b1) ----------------
// lane reads uint `lane` of each gathered row -> features {lane, lane+64,
// lane+128, lane+192}. 16 edges in flight per wave-iter (R8 body).
__global__ __launch_bounds__(256, 6) void spmm1_kernel(
    const int* __restrict__ rp, const int2* __restrict__ epack,
    const unsigned int* __restrict__ T1f8, const float* __restrict__ b1,
    float* __restrict__ mid, int M) {
  const int lane = threadIdx.x & 63;
  const int r = blockIdx.x * 4 + (threadIdx.x >> 6);
  if (r >= M) return;
  const int eend = rp[r];
  int e = (r == 0) ? 0 : rp[r - 1];
  float a0 = 0.f, a1 = 0.f, a2 = 0.f, a3 = 0.f;
  if (e < eend && (e & 1)) {  // align to even for int4 loads
    int2 m = epack[e];
    float v = __int_as_float(m.y);
    unsigned int u = T1f8[(((unsigned)m.x) << 6) | lane];
    floatx2 lo = __builtin_amdgcn_cvt_pk_f32_fp8(u, false);
    floatx2 hi = __builtin_amdgcn_cvt_pk_f32_fp8(u, true);
    a0 += v * lo[0]; a1 += v * lo[1]; a2 += v * hi[0]; a3 += v * hi[1];
    e++;
  }
  // ---- main: 16 edges in flight ----
  for (; e + 15 < eend; e += 16) {
    int4 pA = *(const int4*)(epack + e);
    int4 pB = *(const int4*)(epack + e + 2);
    int4 pC = *(const int4*)(epack + e + 4);
    int4 pD = *(const int4*)(epack + e + 6);
    int4 pE = *(const int4*)(epack + e + 8);
    int4 pF = *(const int4*)(epack + e + 10);
    int4 pG = *(const int4*)(epack + e + 12);
    int4 pH = *(const int4*)(epack + e + 14);
    unsigned int u0  = T1f8[(((unsigned)pA.x) << 6) | lane];
    unsigned int u1  = T1f8[(((unsigned)pA.z) << 6) | lane];
    unsigned int u2  = T1f8[(((unsigned)pB.x) << 6) | lane];
    unsigned int u3  = T1f8[(((unsigned)pB.z) << 6) | lane];
    unsigned int u4  = T1f8[(((unsigned)pC.x) << 6) | lane];
    unsigned int u5  = T1f8[(((unsigned)pC.z) << 6) | lane];
    unsigned int u6  = T1f8[(((unsigned)pD.x) << 6) | lane];
    unsigned int u7  = T1f8[(((unsigned)pD.z) << 6) | lane];
    unsigned int u8  = T1f8[(((unsigned)pE.x) << 6) | lane];
    unsigned int u9  = T1f8[(((unsigned)pE.z) << 6) | lane];
    unsigned int u10 = T1f8[(((unsigned)pF.x) << 6) | lane];
    unsigned int u11 = T1f8[(((unsigned)pF.z) << 6) | lane];
    unsigned int u12 = T1f8[(((unsigned)pG.x) << 6) | lane];
    unsigned int u13 = T1f8[(((unsigned)pG.z) << 6) | lane];
    unsigned int u14 = T1f8[(((unsigned)pH.x) << 6) | lane];
    unsigned int u15 = T1f8[(((unsigned)pH.z) << 6) | lane];
    float v0  = __int_as_float(pA.y), v1  = __int_as_float(pA.w);
    float v2  = __int_as_float(pB.y), v3  = __int_as_float(pB.w);
    float v4  = __int_as_float(pC.y), v5  = __int_as_float(pC.w);
    float v6  = __int_as_float(pD.y), v7  = __int_as_float(pD.w);
    float v8  = __int_as_float(pE.y), v9  = __int_as_float(pE.w);
    float v10 = __int_as_float(pF.y), v11 = __int_as_float(pF.w);
    float v12 = __int_as_float(pG.y), v13 = __int_as_float(pG.w);
    float v14 = __int_as_float(pH.y), v15 = __int_as_float(pH.w);
    floatx2 lo, hi;
    lo = __builtin_amdgcn_cvt_pk_f32_fp8(u0, false);
    hi = __builtin_amdgcn_cvt_pk_f32_fp8(u0, true);
    a0 += v0 * lo[0]; a1 += v0 * lo[1]; a2 += v0 * hi[0]; a3 += v0 * hi[1];
    lo = __builtin_amdgcn_cvt_pk_f32_fp8(u1, false);
    hi = __builtin_amdgcn_cvt_pk_f32_fp8(u1, true);
    a0 += v1 * lo[0]; a1 += v1 * lo[1]; a2 += v1 * hi[0]; a3 += v1 * hi[1];
    lo = __builtin_amdgcn_cvt_pk_f32_fp8(u2, false);
    hi = __builtin_amdgcn_cvt_pk_f32_fp8(u2, true);
    a0 += v2 * lo[0]; a1 += v2 * lo[1]; a2 += v2 * hi[0]; a3 += v2 * hi[1];
    lo = __builtin_amdgcn_cvt_pk_f32_fp8(u3, false);
    hi = __builtin_amdgcn_cvt_pk_f32_fp8(u3, true);
    a0 += v3 * lo[0]; a1 += v3 * lo[1]; a2 += v3 * hi[0]; a3 += v3 * hi[1];
    lo = __builtin_amdgcn_cvt_pk_f32_fp8(u4, false);
    hi = __builtin_amdgcn_cvt_pk_f32_fp8(u4, true);
    a0 += v4 * lo[0]; a1 += v4 * lo[1]; a2 += v4 * hi[0]; a3 += v4 * hi[1];
    lo = __builtin_amdgcn_cvt_pk_f32_fp8(u5, false);
    hi = __builtin_amdgcn_cvt_pk_f32_fp8(u5, true);
    a0 += v5 * lo[0]; a1 += v5 * lo[1]; a2 += v5 * hi[0]; a3 += v5 * hi[1];
    lo = __builtin_amdgcn_cvt_pk_f32_fp8(u6, false);
    hi = __builtin_amdgcn_cvt_pk_f32_fp8(u6, true);
    a0 += v6 * lo[0]; a1 += v6 * lo[1]; a2 += v6 * hi[0]; a3 += v6 * hi[1];
    lo = __builtin_amdgcn_cvt_pk_f32_fp8(u7, false);
    hi = __builtin_amdgcn_cvt_pk_f32_fp8(u7, true);
    a0 += v7 * lo[0]; a1 += v7 * lo[1]; a2 += v7 * hi[0]; a3 += v7 * hi[1];
    lo = __builtin_amdgcn_cvt_pk_f32_fp8(u8, false);
    hi = __builtin_amdgcn_cvt_pk_f32_fp8(u8, true);
    a0 += v8 * lo[0]; a1 += v8 * lo[1]; a2 += v8 * hi[0]; a3 += v8 * hi[1];
    lo = __builtin_amdgcn_cvt_pk_f32_fp8(u9, false);
    hi = __builtin_amdgcn_cvt_pk_f32_fp8(u9, true);
    a0 += v9 * lo[0]; a1 += v9 * lo[1]; a2 += v9 * hi[0]; a3 += v9 * hi[1];
    lo = __builtin_amdgcn_cvt_pk_f32_fp8(u10, false);
    hi = __builtin_amdgcn_cvt_pk_f32_fp8(u10, true);
    a0 += v10 * lo[0]; a1 += v10 * lo[1]; a2 += v10 * hi[0]; a3 += v10 * hi[1];
    lo = __builtin_amdgcn_cvt_pk_f32_fp8(u11, false);
    hi = __builtin_amdgcn_cvt_pk_f32_fp8(u11, true);
    a0 += v11 * lo[0]; a1 += v11 * lo[1]; a2 += v11 * hi[0]; a3 += v11 * hi[1];
    lo = __builtin_amdgcn_cvt_pk_f32_fp8(u12, false);
    hi = __builtin_amdgcn_cvt_pk_f32_fp8(u12, true);
    a0 += v12 * lo[0]; a1 += v12 * lo[1]; a2 += v12 * hi[0]; a3 += v12 * hi[1];
    lo = __builtin_amdgcn_cvt_pk_f32_fp8(u13, false);
    hi = __builtin_amdgcn_cvt_pk_f32_fp8(u13, true);
    a0 += v13 * lo[0]; a1 += v13 * lo[1]; a2 += v13 * hi[0]; a3 += v13 * hi[1];
    lo = __builtin_amdgcn_cvt_pk_f32_fp8(u14, false);
    hi = __builtin_amdgcn_cvt_pk_f32_fp8(u14, true);
    a0 += v14 * lo[0]; a1 += v14 * lo[1]; a2 += v14 * hi[0]; a3 += v14 * hi[1];
    lo = __builtin_amdgcn_cvt_pk_f32_fp8(u15, false);
    hi = __builtin_amdgcn_cvt_pk_f32_fp8(u15, true);
    a0 += v15 * lo[0]; a1 += v15 * lo[1]; a2 += v15 * hi[0]; a3 += v15 * hi[1];
  }
  // ---- 8-edge tail ----
  for (; e + 7 < eend; e += 8) {
    int4 p01 = *(const int4*)(epack + e);
    int4 p23 = *(const int4*)(epack + e + 2);
    int4 p45 = *(const int4*)(epack + e + 4);
    int4 p67 = *(const int4*)(epack + e + 6);
    unsigned int u0 = T1f8[(((unsigned)p01.x) << 6) | lane];
    unsigned int u1 = T1f8[(((unsigned)p01.z) << 6) | lane];
    unsigned int u2 = T1f8[(((unsigned)p23.x) << 6) | lane];
    unsigned int u3 = T1f8[(((unsigned)p23.z) << 6) | lane];
    unsigned int u4 = T1f8[(((unsigned)p45.x) << 6) | lane];
    unsigned int u5 = T1f8[(((unsigned)p45.z) << 6) | lane];
    unsigned int u6 = T1f8[(((unsigned)p67.x) << 6) | lane];
    unsigned int u7 = T1f8[(((unsigned)p67.z) << 6) | lane];
    float v0 = __int_as_float(p01.y), v1 = __int_as_float(p01.w);
    float v2 = __int_as_float(p23.y), v3 = __int_as_float(p23.w);
    float v4 = __int_as_float(p45.y), v5 = __int_as_float(p45.w);
    float v6 = __int_as_float(p67.y), v7 = __int_as_float(p67.w);
    floatx2 lo, hi;
    lo = __builtin_amdgcn_cvt_pk_f32_fp8(u0, false);
    hi = __builtin_amdgcn_cvt_pk_f32_fp8(u0, true);
    a0 += v0 * lo[0]; a1 += v0 * lo[1]; a2 += v0 * hi[0]; a3 += v0 * hi[1];
    lo = __builtin_amdgcn_cvt_pk_f32_fp8(u1, false);
    hi = __builtin_amdgcn_cvt_pk_f32_fp8(u1, true);
    a0 += v1 * lo[0]; a1 += v1 * lo[1]; a2 += v1 * hi[0]; a3 += v1 * hi[1];
    lo = __builtin_amdgcn_cvt_pk_f32_fp8(u2, false);
    hi = __builtin_amdgcn_cvt_pk_f32_fp8(u2, true);
    a0 += v2 * lo[0]; a1 += v2 * lo[1]; a2 += v2 * hi[0]; a3 += v2 * hi[1];
    lo = __builtin_amdgcn_cvt_pk_f32_fp8(u3, false);
    hi = __builtin_amdgcn_cvt_pk_f32_fp8(u3, true);
    a0 += v3 * lo[0]; a1 += v3 * lo[1]; a2 += v3 * hi[0]; a3 += v3 * hi[1];
    lo = __builtin_amdgcn_cvt_pk_f32_fp8(u4, false);
    hi = __builtin_amdgcn_cvt_pk_f32_fp8(u4, true);
    a0 += v4 * lo[0]; a1 += v4 * lo[1]; a2 += v4 * hi[0]; a3 += v4 * hi[1];
    lo = __builtin_amdgcn_cvt_pk_f32_fp8(u5, false);
    hi = __builtin_amdgcn_cvt_pk_f32_fp8(u5, true);
    a0 += v5 * lo[0]; a1 += v5 * lo[1]; a2 += v5 * hi[0]; a3 += v5 * hi[1];
    lo = __builtin_amdgcn_cvt_pk_f32_fp8(u6, false);
    hi = __builtin_amdgcn_cvt_pk_f32_fp8(u6, true);
    a0 += v6 * lo[0]; a1 += v6 * lo[1]; a2 += v6 * hi[0]; a3 += v6 * hi[1];
    lo = __builtin_amdgcn_cvt_pk_f32_fp8(u7, false);
    hi = __builtin_amdgcn_cvt_pk_f32_fp8(u7, true);
    a0 += v7 * lo[0]; a1 += v7 * lo[1]; a2 += v7 * hi[0]; a3 += v7 * hi[1];
  }
  for (; e + 3 < eend; e += 4) {
    int4 p01 = *(const int4*)(epack + e);
    int4 p23 = *(const int4*)(epack + e + 2);
    unsigned int u0 = T1f8[(((unsigned)p01.x) << 6) | lane];
    unsigned int u1 = T1f8[(((unsigned)p01.z) << 6) | lane];
    unsigned int u2 = T1f8[(((unsigned)p23.x) << 6) | lane];
    unsigned int u3 = T1f8[(((unsigned)p23.z) << 6) | lane];
    float v0 = __int_as_float(p01.y), v1 = __int_as_float(p01.w);
    float v2 = __int_as_float(p23.y), v3 = __int_as_float(p23.w);
    floatx2 lo, hi;
    lo = __builtin_amdgcn_cvt_pk_f32_fp8(u0, false);
    hi = __builtin_amdgcn_cvt_pk_f32_fp8(u0, true);
    a0 += v0 * lo[0]; a1 += v0 * lo[1]; a2 += v0 * hi[0]; a3 += v0 * hi[1];
    lo = __builtin_amdgcn_cvt_pk_f32_fp8(u1, false);
    hi = __builtin_amdgcn_cvt_pk_f32_fp8(u1, true);
    a0 += v1 * lo[0]; a1 += v1 * lo[1]; a2 += v1 * hi[0]; a3 += v1 * hi[1];
    lo = __builtin_amdgcn_cvt_pk_f32_fp8(u2, false);
    hi = __builtin_amdgcn_cvt_pk_f32_fp8(u2, true);
    a0 += v2 * lo[0]; a1 += v2 * lo[1]; a2 += v2 * hi[0]; a3 += v2 * hi[1];
    lo = __builtin_amdgcn_cvt_pk_f32_fp8(u3, false);
    hi = __builtin_amdgcn_cvt_pk_f32_fp8(u3, true);
    a0 += v3 * lo[0]; a1 += v3 * lo[1]; a2 += v3 * hi[0]; a3 += v3 * hi[1];
  }
  for (; e < eend; e++) {
    int2 m = epack[e];
    float v = __int_as_float(m.y);
    unsigned int u = T1f8[(((unsigned)m.x) << 6) | lane];
    floatx2 lo = __builtin_amdgcn_cvt_pk_f32_fp8(u, false);
    floatx2 hi = __builtin_amdgcn_cvt_pk_f32_fp8(u, true);
    a0 += v * lo[0]; a1 += v * lo[1]; a2 += v * hi[0]; a3 += v * hi[1];
  }
  // a0..a3 are features lane, lane+64, lane+128, lane+192
  float o0 = fmaxf(a0 + b1[lane],       0.f);
  float o1 = fmaxf(a1 + b1[lane + 64],  0.f);
  float o2 = fmaxf(a2 + b1[lane + 128], 0.f);
  float o3 = fmaxf(a3 + b1[lane + 192], 0.f);
  float* mrow = mid + (size_t)r * 256 + lane;
  mrow[0]   = o0;
  mrow[64]  = o1;
  mrow[128] = o2;
  mrow[192] = o3;
}

// ---------------- GEMM2: T2f8 = fp8(mid @ W2), frag-linear LDS + reg dbuf ----------------
// T2f8 layout: uint i of row n packs cols {i, i+16, i+32} (byte3 = 0).
__global__ __launch_bounds__(256) void gemm2_kernel(const float* __restrict__ mid,
                                                    const bf16* __restrict__ W2T,
                                                    unsigned int* __restrict__ T2f8, int M) {
  __shared__ __align__(16) bf16 Asf[4 * 512];   // 4KB
  __shared__ __align__(16) bf16 Bsf[3 * 512];   // 3KB
  const int t = threadIdx.x;
  const int wave = t >> 6, lane = t & 63;
  const int quad = lane >> 4, l16 = lane & 15;
  const int m0 = blockIdx.x * 64;
  floatx4 acc[3] = {};
  const int ar = t >> 2, aq = t & 3;
  const int a_gr = m0 + ar;
  const bool a_ok = (a_gr < M);
  const float* a_src = mid + (size_t)a_gr * 256 + aq * 8;
  const int aslot = (ar >> 4) * 512 + (aq * 16 + (ar & 15)) * 8;
  const bool b_ok = (t < 192);
  const bf16* bsrc = W2T + (size_t)((t >> 6) * 16 + (t & 15)) * 256 + ((t >> 4) & 3) * 8;

  // prologue: prefetch k0 = 0
  float4 f0 = {0,0,0,0}, f1 = {0,0,0,0};
  if (a_ok) {
    const float4* p = (const float4*)a_src;
    f0 = p[0]; f1 = p[1];
  }
  bf16x8 bq = {};
  if (b_ok) bq = *(const bf16x8*)(bsrc);

  for (int k0 = 0; k0 < 256; k0 += 32) {
    __syncthreads();
    {
      bf16x8 av;
      av[0] = (bf16)f0.x; av[1] = (bf16)f0.y; av[2] = (bf16)f0.z; av[3] = (bf16)f0.w;
      av[4] = (bf16)f1.x; av[5] = (bf16)f1.y; av[6] = (bf16)f1.z; av[7] = (bf16)f1.w;
      *(bf16x8*)&Asf[aslot] = av;
      if (b_ok) *(bf16x8*)&Bsf[(size_t)t * 8] = bq;
    }
    __syncthreads();
    if (k0 + 32 < 256) {  // prefetch next k-step; overlaps MFMA below
      f0 = make_float4(0.f, 0.f, 0.f, 0.f);
      f1 = make_float4(0.f, 0.f, 0.f, 0.f);
      if (a_ok) {
        const float4* p = (const float4*)(a_src + k0 + 32);
        f0 = p[0]; f1 = p[1];
      }
      if (b_ok) bq = *(const bf16x8*)(bsrc + k0 + 32);
    }
    __builtin_amdgcn_sched_barrier(0);  // pin prefetch issue before MFMA section
    bf16x8 a = *(const bf16x8*)&Asf[wave * 512 + lane * 8];
#pragma unroll
    for (int nt = 0; nt < 3; nt++) {
      bf16x8 b = *(const bf16x8*)&Bsf[nt * 512 + lane * 8];
      acc[nt] = __builtin_amdgcn_mfma_f32_16x16x32_bf16(a, b, acc[nt], 0, 0, 0);
    }
  }
  const int row_base = m0 + wave * 16 + quad * 4;
#pragma unroll
  for (int j = 0; j < 4; j++) {
    int gr = row_base + j;
    if (gr < M) {
      int p = 0;
      p = __builtin_amdgcn_cvt_pk_fp8_f32(acc[0][j], acc[1][j], p, false);
      p = __builtin_amdgcn_cvt_pk_fp8_f32(acc[2][j], 0.0f,      p, true);
      T2f8[(size_t)gr * 16 + l16] = (unsigned int)p;
    }
  }
}

// ---------------- SpMM2: out = gather-sum(T2f8) + b2 ----------------
// quarter-wave (16 lanes) per edge; 16 edges per wave-iter (4/group);
// lane q reads uint q -> cols {q, q+16, q+32}. shfl-tree combine.
__global__ __launch_bounds__(256, 6) void spmm2_kernel(
    const int* __restrict__ rp, const int2* __restrict__ epack,
    const unsigned int* __restrict__ T2f8, const float* __restrict__ b2,
    float* __restrict__ out2, int M) {
  const int lane = threadIdx.x & 63;
  const int r = blockIdx.x * 4 + (threadIdx.x >> 6);
  if (r >= M) return;
  const int q = lane & 15;
  const int g = lane >> 4;  // edge group 0..3
  const int eend = rp[r];
  int e = (r == 0) ? 0 : rp[r - 1];
  float a0 = 0.f, a1 = 0.f, a2 = 0.f;
  if (e < eend && (e & 1)) {  // align to even for int4 loads (group 0 takes it)
    if (g == 0) {
      int2 m = epack[e];
      float v = __int_as_float(m.y);
      unsigned int u = T2f8[(((unsigned)m.x) << 4) | q];
      floatx2 lo = __builtin_amdgcn_cvt_pk_f32_fp8(u, false);
      floatx2 hi = __builtin_amdgcn_cvt_pk_f32_fp8(u, true);
      a0 += v * lo[0]; a1 += v * lo[1]; a2 += v * hi[0];
    }
    e++;
  }
  // ---- main: 16 edges / wave-iter, group g: e+2g,e+2g+1,e+8+2g,e+8+2g+1 ----
  for (; e + 15 < eend; e += 16) {
    int4 m0 = *(const int4*)(epack + e + 2 * g);
    int4 m1 = *(const int4*)(epack + e + 8 + 2 * g);
    unsigned int u0 = T2f8[(((unsigned)m0.x) << 4) | q];
    unsigned int u1 = T2f8[(((unsigned)m0.z) << 4) | q];
    unsigned int u2 = T2f8[(((unsigned)m1.x) << 4) | q];
    unsigned int u3 = T2f8[(((unsigned)m1.z) << 4) | q];
    float v0 = __int_as_float(m0.y), v1 = __int_as_float(m0.w);
    float v2 = __int_as_float(m1.y), v3 = __int_as_float(m1.w);
    floatx2 lo, hi;
    lo = __builtin_amdgcn_cvt_pk_f32_fp8(u0, false);
    hi = __builtin_amdgcn_cvt_pk_f32_fp8(u0, true);
    a0 += v0 * lo[0]; a1 += v0 * lo[1]; a2 += v0 * hi[0];
    lo = __builtin_amdgcn_cvt_pk_f32_fp8(u1, false);
    hi = __builtin_amdgcn_cvt_pk_f32_fp8(u1, true);
    a0 += v1 * lo[0]; a1 += v1 * lo[1]; a2 += v1 * hi[0];
    lo = __builtin_amdgcn_cvt_pk_f32_fp8(u2, false);
    hi = __builtin_amdgcn_cvt_pk_f32_fp8(u2, true);
    a0 += v2 * lo[0]; a1 += v2 * lo[1]; a2 += v2 * hi[0];
    lo = __builtin_amdgcn_cvt_pk_f32_fp8(u3, false);
    hi = __builtin_amdgcn_cvt_pk_f32_fp8(u3, true);
    a0 += v3 * lo[0]; a1 += v3 * lo[1]; a2 += v3 * hi[0];
  }
  for (; e + 7 < eend; e += 8) {  // group g: edges e+2g, e+2g+1 via one int4
    int4 m = *(const int4*)(epack + e + 2 * g);
    float v0 = __int_as_float(m.y), v1 = __int_as_float(m.w);
    unsigned int u0 = T2f8[(((unsigned)m.x) << 4) | q];
    unsigned int u1 = T2f8[(((unsigned)m.z) << 4) | q];
    floatx2 l0 = __builtin_amdgcn_cvt_pk_f32_fp8(u0, false);
    floatx2 h0 = __builtin_amdgcn_cvt_pk_f32_fp8(u0, true);
    floatx2 l1 = __builtin_amdgcn_cvt_pk_f32_fp8(u1, false);
    floatx2 h1 = __builtin_amdgcn_cvt_pk_f32_fp8(u1, true);
    a0 += v0 * l0[0]; a1 += v0 * l0[1]; a2 += v0 * h0[0];
    a0 += v1 * l1[0]; a1 += v1 * l1[1]; a2 += v1 * h1[0];
  }
  for (; e + 3 < eend; e += 4) {  // group g: edge e+g
    int2 m = epack[e + g];
    float v = __int_as_float(m.y);
    unsigned int u = T2f8[(((unsigned)m.x) << 4) | q];
    floatx2 lo = __builtin_amdgcn_cvt_pk_f32_fp8(u, false);
    floatx2 hi = __builtin_amdgcn_cvt_pk_f32_fp8(u, true);
    a0 += v * lo[0]; a1 += v * lo[1]; a2 += v * hi[0];
  }
  if (e + g < eend) {  // tail: groups 0..(eend-e-1)
    int2 m = epack[e + g];
    float v = __int_as_float(m.y);
    unsigned int u = T2f8[(((unsigned)m.x) << 4) | q];
    floatx2 lo = __builtin_amdgcn_cvt_pk_f32_fp8(u, false);
    floatx2 hi = __builtin_amdgcn_cvt_pk_f32_fp8(u, true);
    a0 += v * lo[0]; a1 += v * lo[1]; a2 += v * hi[0];
  }
  a0 += __shfl_down(a0, 32, 64); a0 += __shfl_down(a0, 16, 64);
  a1 += __shfl_down(a1, 32, 64); a1 += __shfl_down(a1, 16, 64);
  a2 += __shfl_down(a2, 32, 64); a2 += __shfl_down(a2, 16, 64);
  if (lane < 16) {
    // a0..a2 are cols lane, lane+16, lane+32 (valid cols < 40)
    float* orow = out2 + (size_t)r * 40;
    orow[lane]      = a0 + b2[lane];
    orow[lane + 16] = a1 + b2[lane + 16];
    if (lane < 8) orow[lane + 32] = a2 + b2[lane + 32];
  }
}

// ---------------- launch ----------------
extern "C" void kernel_launch(void* const* d_in, const int* in_sizes, int n_in,
                              void* d_out, int out_size, void* d_ws, size_t ws_size,
                              hipStream_t stream) {
  const float* x        = (const float*)d_in[0];
  const int*   edge_row = (const int*)d_in[1];
  const int*   edge_col = (const int*)d_in[2];
  const float* edge_val = (const float*)d_in[3];
  const float* W1       = (const float*)d_in[4];
  const float* b1       = (const float*)d_in[5];
  const float* W2       = (const float*)d_in[6];
  const float* b2       = (const float*)d_in[7];
  const int M = in_sizes[0] / 512;  // 100000 nodes
  const int E = in_sizes[1];        // 3200000 edges
  const int NB = (M + 255) >> 8;    // 391 buckets
  const int EBLK = (E + 8191) / 8192;  // 391 blocks

  char* ws = (char*)d_ws;
  size_t off = 0;
  bf16* W1T     = (bf16*)(ws + off);  off += 512 * 256 * 2;
  bf16* W2T     = (bf16*)(ws + off);  off += 48 * 256 * 2;
  unsigned int* T1f8 = (unsigned int*)(ws + off); off += (size_t)M * 256;
  unsigned int* T2f8 = (unsigned int*)(ws + off); off += (size_t)M * 64;
  int* rp       = (int*)(ws + off);   off += (size_t)M * 4;
  int* gbcount  = (int*)(ws + off);   off += NBMAX * 4;
  int* bstart   = (int*)(ws + off);   off += (NBMAX + 1) * 4;
  int* blkcnt   = (int*)(ws + off);   off += (size_t)NB * EBLK * 4;
  int* blkoff   = (int*)(ws + off);   off += (size_t)NB * EBLK * 4;
  off = (off + 15) & ~(size_t)15;
  int2* epack_b = (int2*)(ws + off);  off += (size_t)E * 8;
  int2* epack_f = (int2*)(ws + off);  off += (size_t)E * 8;

  float* mid  = (float*)d_out;
  float* out2 = mid + (size_t)M * 256;

  hipMemsetAsync(gbcount, 0, NBMAX * 4, stream);
  conv_w<<<(512 * 256 + 48 * 256 + 255) / 256, 256, 0, stream>>>(W1, W2, W1T, W2T);
  bhist_kernel<<<EBLK, 256, 0, stream>>>(edge_row, gbcount, blkcnt, E, NB, EBLK);
  bscan_kernel<<<1, 512, 0, stream>>>(gbcount, bstart, NB);
  bscan2_kernel<<<NB, 512, 0, stream>>>(blkcnt, bstart, blkoff, EBLK);
  partA_kernel<<<EBLK, 256, 0, stream>>>(edge_row, edge_col, edge_val,
                                         blkoff, epack_b, E, NB, EBLK);
  partB_kernel<<<NB, 256, 0, stream>>>(epack_b, bstart, epack_f, rp, M);
  gemm1_kernel<<<(M + 63) / 64, 256, 0, stream>>>(x, W1T, T1f8, M);
  spmm1_kernel<<<(M + 3) / 4, 256, 0, stream>>>(rp, epack_f, T1f8, b1, mid, M);
  gemm2_kernel<<<(M + 63) / 64, 256, 0, stream>>>(mid, W2T, T2f8, M);
  spmm2_kernel<<<(M + 3) / 4, 256, 0, stream>>>(rp, epack_f, T2f8, b2, out2, M);
}